// Round 1
// baseline (2807.165 us; speedup 1.0000x reference)
//
#include <hip/hip_runtime.h>
#include <hip/hip_bf16.h>
#include <math.h>

#define NN 40000
#define EE 320000
#define NT 3
#define LL 3
#define DD 128
#define HID 256
#define NH 4
#define CC 64

__device__ __forceinline__ float gelu_f(float x) {
    return 0.5f * x * (1.0f + erff(x * 0.70710678118654752440f));
}
__device__ __forceinline__ float lrelu_f(float x) {
    return x > 0.0f ? x : 0.2f * x;
}

// ---------------- GEMM: C[M,Nc] = A[M,K] @ B[K,Nc] (+bias) ----------------
// BM=BN=64, BK=16, 256 threads, 4x4 per thread. All dims divide evenly here.
__global__ __launch_bounds__(256) void gemm_k(const float* __restrict__ A,
                                              const float* __restrict__ B,
                                              const float* __restrict__ bias,
                                              float* __restrict__ Cc,
                                              int M, int K, int Nc) {
    __shared__ __align__(16) float As[16][68];
    __shared__ __align__(16) float Bs[16][64];
    int bm = blockIdx.y * 64, bn = blockIdx.x * 64;
    int tid = threadIdx.x;
    int tcol = (tid & 15) * 4;
    int trow = (tid >> 4) * 4;
    float acc[4][4] = {};
    for (int k0 = 0; k0 < K; k0 += 16) {
        #pragma unroll
        for (int i = tid; i < 64 * 16; i += 256) {
            int r = i >> 4, c = i & 15;
            As[c][r] = A[(size_t)(bm + r) * K + k0 + c];
        }
        #pragma unroll
        for (int i = tid; i < 16 * 64; i += 256) {
            int r = i >> 6, c = i & 63;
            Bs[r][c] = B[(size_t)(k0 + r) * Nc + bn + c];
        }
        __syncthreads();
        #pragma unroll
        for (int kk = 0; kk < 16; kk++) {
            float4 av = *reinterpret_cast<const float4*>(&As[kk][trow]);
            float4 bv = *reinterpret_cast<const float4*>(&Bs[kk][tcol]);
            float aa[4] = {av.x, av.y, av.z, av.w};
            float bb[4] = {bv.x, bv.y, bv.z, bv.w};
            #pragma unroll
            for (int i2 = 0; i2 < 4; i2++)
                #pragma unroll
                for (int j = 0; j < 4; j++) acc[i2][j] += aa[i2] * bb[j];
        }
        __syncthreads();
    }
    #pragma unroll
    for (int i2 = 0; i2 < 4; i2++) {
        size_t r = bm + trow + i2;
        #pragma unroll
        for (int j = 0; j < 4; j++) {
            int c = bn + tcol + j;
            Cc[r * Nc + c] = acc[i2][j] + (bias ? bias[c] : 0.0f);
        }
    }
}

// ---------------- LayerNorm + GELU over rows of 256 ----------------
__global__ __launch_bounds__(256) void ln_gelu_k(const float* __restrict__ y,
                                                 const float* __restrict__ g,
                                                 const float* __restrict__ b,
                                                 float* __restrict__ out) {
    int n = blockIdx.x, t = threadIdx.x;
    float v = y[(size_t)n * HID + t];
    float s = v, q = v * v;
    #pragma unroll
    for (int o = 32; o; o >>= 1) { s += __shfl_xor(s, o); q += __shfl_xor(q, o); }
    __shared__ float sh[8];
    if ((t & 63) == 0) { sh[t >> 6] = s; sh[4 + (t >> 6)] = q; }
    __syncthreads();
    s = sh[0] + sh[1] + sh[2] + sh[3];
    q = sh[4] + sh[5] + sh[6] + sh[7];
    float mean = s * (1.0f / HID);
    float var = q * (1.0f / HID) - mean * mean;
    float rs = rsqrtf(var + 1e-5f);
    out[(size_t)n * HID + t] = gelu_f(g[t] * (v - mean) * rs + b[t]);
}

// ---------------- edge-weight gate ----------------
__global__ void ewg_hist_k(const int* __restrict__ ei, const float* __restrict__ ew,
                           float* __restrict__ wsum, float* __restrict__ deg) {
    int gid = blockIdx.x * 256 + threadIdx.x;
    if (gid >= NT * EE) return;
    int t = gid / EE, e = gid - t * EE;
    int dst = ei[(size_t)t * 2 * EE + EE + e];
    atomicAdd(&wsum[dst], ew[gid]);
    atomicAdd(&deg[dst], 1.0f);
}

__global__ void ewg_k(const float* __restrict__ wsum, const float* __restrict__ deg,
                      float* __restrict__ ewg) {
    int n = blockIdx.x * 256 + threadIdx.x;
    if (n >= NN) return;
    float d = deg[n];
    float m = d > 1.0f ? d : 1.0f;
    float z = wsum[n] / m;
    ewg[n] = 0.5f + 1.0f / (1.0f + expf(-z));
}

// ---------------- CSR build ----------------
__global__ void cnt_hist_k(const int* __restrict__ dsts, int* __restrict__ cnt) {
    int e = blockIdx.x * 256 + threadIdx.x;
    if (e >= EE) return;
    atomicAdd(&cnt[dsts[e]], 1);
}

__global__ __launch_bounds__(1024) void scan_excl_k(const int* __restrict__ cnt,
                                                    int* __restrict__ off, int n, int total) {
    __shared__ int sh[1024];
    __shared__ int carry_s;
    if (threadIdx.x == 0) carry_s = 0;
    __syncthreads();
    for (int base = 0; base < n; base += 1024) {
        int i = base + threadIdx.x;
        int v = (i < n) ? cnt[i] : 0;
        sh[threadIdx.x] = v;
        __syncthreads();
        for (int o = 1; o < 1024; o <<= 1) {
            int tv = (threadIdx.x >= (unsigned)o) ? sh[threadIdx.x - o] : 0;
            __syncthreads();
            sh[threadIdx.x] += tv;
            __syncthreads();
        }
        int incl = sh[threadIdx.x];
        int c0 = carry_s;
        if (i < n) off[i] = c0 + incl - v;
        __syncthreads();
        if (threadIdx.x == 1023) carry_s = c0 + sh[1023];
        __syncthreads();
    }
    if (threadIdx.x == 0) off[n] = total;
}

__global__ void scatter_k(const int* __restrict__ srcs, const int* __restrict__ dsts,
                          const int* __restrict__ off, int* __restrict__ cnt,
                          int* __restrict__ rsrc) {
    int e = blockIdx.x * 256 + threadIdx.x;
    if (e >= EE) return;
    int d = dsts[e];
    int pos = off[d] + atomicAdd(&cnt[d], 1);
    rsrc[pos] = srcs[e];
}

// ---------------- per-(node,head) attention score inputs ----------------
__global__ __launch_bounds__(256) void compute_s_k(const float* __restrict__ xp,
                                                   const float* __restrict__ asrc,
                                                   const float* __restrict__ adst,
                                                   float* __restrict__ ssrc,
                                                   float* __restrict__ sdst) {
    int node = blockIdx.x * 4 + (threadIdx.x >> 6);
    int lane = threadIdx.x & 63;
    if (node >= NN) return;
    #pragma unroll
    for (int h = 0; h < NH; h++) {
        float v = xp[(size_t)node * HID + h * CC + lane];
        float p = v * asrc[h * CC + lane];
        float q = v * adst[h * CC + lane];
        #pragma unroll
        for (int o = 32; o; o >>= 1) { p += __shfl_xor(p, o); q += __shfl_xor(q, o); }
        if (lane == 0) {
            ssrc[node * NH + h] = p;
            sdst[node * NH + h] = q;
        }
    }
}

// ---------------- init agg with sum of per-type biases ----------------
__global__ void agg_init_k(const float* __restrict__ gb, float* __restrict__ agg) {
    size_t idx = (size_t)blockIdx.x * 256 + threadIdx.x;
    if (idx >= (size_t)NN * HID) return;
    int m = idx & 255;
    agg[idx] = gb[m] + gb[HID + m] + gb[2 * HID + m];
}

// ---------------- GAT aggregation: one node per 64-lane wave ----------------
__global__ __launch_bounds__(256) void gat_agg_k(const float* __restrict__ xp,
                                                 const float* __restrict__ ssrc,
                                                 const float* __restrict__ sdst,
                                                 const int* __restrict__ roff,
                                                 const int* __restrict__ rsrc,
                                                 float* __restrict__ agg) {
    int node = blockIdx.x * 4 + (threadIdx.x >> 6);
    int lane = threadIdx.x & 63;
    if (node >= NN) return;
    int beg = roff[node], end = roff[node + 1];
    if (beg == end) return;  // no in-edges: agg keeps bias only
    float4 sd = *reinterpret_cast<const float4*>(&sdst[node * NH]);
    float m0 = -INFINITY, m1 = -INFINITY, m2 = -INFINITY, m3 = -INFINITY;
    for (int e = beg; e < end; e++) {
        int s = rsrc[e];
        float4 ss = *reinterpret_cast<const float4*>(&ssrc[s * NH]);
        m0 = fmaxf(m0, lrelu_f(ss.x + sd.x));
        m1 = fmaxf(m1, lrelu_f(ss.y + sd.y));
        m2 = fmaxf(m2, lrelu_f(ss.z + sd.z));
        m3 = fmaxf(m3, lrelu_f(ss.w + sd.w));
    }
    float d0 = 0, d1 = 0, d2 = 0, d3 = 0;
    float a0 = 0, a1 = 0, a2 = 0, a3 = 0;
    for (int e = beg; e < end; e++) {
        int s = rsrc[e];
        float4 ss = *reinterpret_cast<const float4*>(&ssrc[s * NH]);
        const float* xr = xp + (size_t)s * HID;
        float w0 = expf(lrelu_f(ss.x + sd.x) - m0);
        float w1 = expf(lrelu_f(ss.y + sd.y) - m1);
        float w2 = expf(lrelu_f(ss.z + sd.z) - m2);
        float w3 = expf(lrelu_f(ss.w + sd.w) - m3);
        d0 += w0; d1 += w1; d2 += w2; d3 += w3;
        a0 += w0 * xr[0 * CC + lane];
        a1 += w1 * xr[1 * CC + lane];
        a2 += w2 * xr[2 * CC + lane];
        a3 += w3 * xr[3 * CC + lane];
    }
    float* ar = agg + (size_t)node * HID;
    ar[0 * CC + lane] += a0 / (d0 + 1e-16f);
    ar[1 * CC + lane] += a1 / (d1 + 1e-16f);
    ar[2 * CC + lane] += a2 / (d2 + 1e-16f);
    ar[3 * CC + lane] += a3 / (d3 + 1e-16f);
}

// ---------------- gate + edge-weight gate + residual + LN + GELU ----------------
__global__ __launch_bounds__(256) void gate_res_ln_k(const float* __restrict__ agg,
                                                     const float* hin,
                                                     const float* __restrict__ liq,
                                                     const float* __restrict__ gW,
                                                     const float* __restrict__ gb,
                                                     const float* __restrict__ ewg,
                                                     const float* __restrict__ lg,
                                                     const float* __restrict__ lb,
                                                     float* hout) {
    int n = blockIdx.x, t = threadIdx.x;
    float a = agg[(size_t)n * HID + t];
    float hh = hin[(size_t)n * HID + t];
    float part = a * gW[t];
    if (t < 4) part += liq[n * 4 + t] * gW[HID + t];
    #pragma unroll
    for (int o = 32; o; o >>= 1) part += __shfl_xor(part, o);
    __shared__ float sh[12];
    if ((t & 63) == 0) sh[t >> 6] = part;
    __syncthreads();
    float logit = sh[0] + sh[1] + sh[2] + sh[3] + gb[0];
    float gate = 1.0f / (1.0f + expf(-logit));
    float v = (gate * a + (1.0f - gate) * hh) * ewg[n] + hh;
    float s = v, q = v * v;
    #pragma unroll
    for (int o = 32; o; o >>= 1) { s += __shfl_xor(s, o); q += __shfl_xor(q, o); }
    if ((t & 63) == 0) { sh[4 + (t >> 6)] = s; sh[8 + (t >> 6)] = q; }
    __syncthreads();
    s = sh[4] + sh[5] + sh[6] + sh[7];
    q = sh[8] + sh[9] + sh[10] + sh[11];
    float mean = s * (1.0f / HID);
    float var = q * (1.0f / HID) - mean * mean;
    float rs = rsqrtf(var + 1e-5f);
    hout[(size_t)n * HID + t] = gelu_f(lg[t] * (v - mean) * rs + lb[t]);
}

// ---------------- column partial sums of ho (N x D) ----------------
__global__ __launch_bounds__(128) void colpart_k(const float* __restrict__ ho,
                                                 float* __restrict__ part) {
    int c = threadIdx.x, b = blockIdx.x;
    float s = 0.0f;
    for (int r = b; r < NN; r += 256) s += ho[(size_t)r * DD + c];
    part[b * DD + c] = s;
}

// ---------------- readout MLP (single block) ----------------
__global__ __launch_bounds__(256) void readout_k(const float* __restrict__ part,
                                                 const float* __restrict__ W1,
                                                 const float* __restrict__ b1,
                                                 const float* __restrict__ W2,
                                                 const float* __restrict__ b2,
                                                 float* __restrict__ surf) {
    __shared__ float m[DD];
    __shared__ float a1[HID];
    int t = threadIdx.x;
    if (t < DD) {
        float s = 0.0f;
        for (int b = 0; b < 256; b++) s += part[b * DD + t];
        m[t] = s / (float)NN;
    }
    __syncthreads();
    float s1 = b1[t];
    for (int k = 0; k < DD; k++) s1 += m[k] * W1[k * HID + t];
    a1[t] = gelu_f(s1);
    __syncthreads();
    float s2 = b2[t];
    for (int k = 0; k < HID; k++) s2 += a1[k] * W2[k * HID + t];
    surf[t] = s2;
}

extern "C" void kernel_launch(void* const* d_in, const int* in_sizes, int n_in,
                              void* d_out, int out_size, void* d_ws, size_t ws_size,
                              hipStream_t stream) {
    const float* x       = (const float*)d_in[0];
    const float* liq     = (const float*)d_in[1];
    const int*   ei      = (const int*)d_in[2];
    const float* ew      = (const float*)d_in[3];
    const float* in_W    = (const float*)d_in[4];
    const float* in_b    = (const float*)d_in[5];
    const float* in_g    = (const float*)d_in[6];
    const float* in_bb   = (const float*)d_in[7];
    const float* gat_W   = (const float*)d_in[8];
    const float* gat_as  = (const float*)d_in[9];
    const float* gat_ad  = (const float*)d_in[10];
    const float* gat_b   = (const float*)d_in[11];
    const float* ln_g    = (const float*)d_in[12];
    const float* ln_b    = (const float*)d_in[13];
    const float* gate_W  = (const float*)d_in[14];
    const float* gate_b  = (const float*)d_in[15];
    const float* out_W1  = (const float*)d_in[16];
    const float* out_b1  = (const float*)d_in[17];
    const float* out_g   = (const float*)d_in[18];
    const float* out_bb  = (const float*)d_in[19];
    const float* out_W2  = (const float*)d_in[20];
    const float* out_b2  = (const float*)d_in[21];
    const float* ro_W1   = (const float*)d_in[22];
    const float* ro_b1   = (const float*)d_in[23];
    const float* ro_W2   = (const float*)d_in[24];
    const float* ro_b2   = (const float*)d_in[25];

    float* out = (float*)d_out;
    float* out_ho   = out;
    float* out_surf = out + (size_t)NN * DD;
    float* out_h[3];
    out_h[0] = out_surf + HID;
    out_h[1] = out_h[0] + (size_t)NN * HID;
    out_h[2] = out_h[1] + (size_t)NN * HID;

    float* ws = (float*)d_ws;
    size_t off = 0;
    float* xp   = ws + off; off += (size_t)NN * HID;
    float* agg  = ws + off; off += (size_t)NN * HID;
    float* ssrc = ws + off; off += (size_t)NN * NH;
    float* sdst = ws + off; off += (size_t)NN * NH;
    float* ewg  = ws + off; off += NN;
    float* wsum = ws + off; off += NN;
    float* deg  = ws + off; off += NN;
    float* cpart = ws + off; off += 256 * DD;
    int* csr_off = (int*)(ws + off);
    int* csr_src = csr_off + NT * (NN + 1);
    int* cnt     = csr_src + (size_t)NT * EE;

    // ---- input projection + LN + GELU -> h0 (stored in h1 region) ----
    gemm_k<<<dim3(HID / 64, NN / 64), 256, 0, stream>>>(x, in_W, in_b, xp, NN, DD, HID);
    ln_gelu_k<<<NN, 256, 0, stream>>>(xp, in_g, in_bb, out_h[0]);

    // ---- edge-weight gate ----
    hipMemsetAsync(wsum, 0, NN * sizeof(float), stream);
    hipMemsetAsync(deg, 0, NN * sizeof(float), stream);
    ewg_hist_k<<<(NT * EE + 255) / 256, 256, 0, stream>>>(ei, ew, wsum, deg);
    ewg_k<<<(NN + 255) / 256, 256, 0, stream>>>(wsum, deg, ewg);

    // ---- CSR build (by dst) per edge type ----
    for (int t = 0; t < NT; t++) {
        const int* srcs = ei + (size_t)t * 2 * EE;
        const int* dsts = srcs + EE;
        int* off_t = csr_off + t * (NN + 1);
        int* rsrc_t = csr_src + (size_t)t * EE;
        hipMemsetAsync(cnt, 0, NN * sizeof(int), stream);
        cnt_hist_k<<<(EE + 255) / 256, 256, 0, stream>>>(dsts, cnt);
        scan_excl_k<<<1, 1024, 0, stream>>>(cnt, off_t, NN, EE);
        hipMemsetAsync(cnt, 0, NN * sizeof(int), stream);
        scatter_k<<<(EE + 255) / 256, 256, 0, stream>>>(srcs, dsts, off_t, cnt, rsrc_t);
    }

    // ---- message-passing layers ----
    const float* hcur = out_h[0];
    for (int i = 0; i < LL; i++) {
        agg_init_k<<<((size_t)NN * HID + 255) / 256, 256, 0, stream>>>(gat_b + (size_t)i * NT * HID, agg);
        for (int t = 0; t < NT; t++) {
            int wi = i * NT + t;
            gemm_k<<<dim3(HID / 64, NN / 64), 256, 0, stream>>>(
                hcur, gat_W + (size_t)wi * HID * HID, nullptr, xp, NN, HID, HID);
            compute_s_k<<<NN / 4, 256, 0, stream>>>(
                xp, gat_as + (size_t)wi * NH * CC, gat_ad + (size_t)wi * NH * CC, ssrc, sdst);
            gat_agg_k<<<NN / 4, 256, 0, stream>>>(
                xp, ssrc, sdst, csr_off + t * (NN + 1), csr_src + (size_t)t * EE, agg);
        }
        gate_res_ln_k<<<NN, 256, 0, stream>>>(agg, hcur, liq, gate_W, gate_b, ewg,
                                              ln_g + i * HID, ln_b + i * HID, out_h[i]);
        hcur = out_h[i];
    }

    // ---- output head ----
    gemm_k<<<dim3(HID / 64, NN / 64), 256, 0, stream>>>(hcur, out_W1, out_b1, xp, NN, HID, HID);
    ln_gelu_k<<<NN, 256, 0, stream>>>(xp, out_g, out_bb, agg);
    gemm_k<<<dim3(DD / 64, NN / 64), 256, 0, stream>>>(agg, out_W2, out_b2, out_ho, NN, HID, DD);

    // ---- readout ----
    colpart_k<<<256, 128, 0, stream>>>(out_ho, cpart);
    readout_k<<<1, 256, 0, stream>>>(cpart, ro_W1, ro_b1, ro_W2, ro_b2, out_surf);
}

// Round 3
// 1050.917 us; speedup vs baseline: 2.6712x; 2.6712x over previous
//
#include <hip/hip_runtime.h>
#include <hip/hip_bf16.h>
#include <math.h>

#define NN 40000
#define EE 320000
#define NT 3
#define LL 3
#define DD 128
#define HID 256
#define NH 4
#define CC 64

typedef __attribute__((ext_vector_type(8))) short short8;
typedef __attribute__((ext_vector_type(4))) float f32x4;

__device__ __forceinline__ float gelu_f(float x) {
    return 0.5f * x * (1.0f + erff(x * 0.70710678118654752440f));
}
__device__ __forceinline__ float lrelu_f(float x) {
    return x > 0.0f ? x : 0.2f * x;
}
__device__ __forceinline__ float bf2f(unsigned short u) {
    unsigned int x = ((unsigned int)u) << 16;
    float f;
    __builtin_memcpy(&f, &x, 4);
    return f;
}
__device__ __forceinline__ unsigned short f2bf(float f) {
    __hip_bfloat16 h = __float2bfloat16(f);
    unsigned short u;
    __builtin_memcpy(&u, &h, 2);
    return u;
}
__device__ __forceinline__ void gload16(const void* g, void* l) {
    __builtin_amdgcn_global_load_lds(
        (const __attribute__((address_space(1))) unsigned int*)g,
        (__attribute__((address_space(3))) unsigned int*)l, 16, 0, 0);
}

// ---------------- weight transpose + bf16 convert: W[m][K][N] -> Wt[m][N][K] ----------------
__global__ void wconv_k(const float* __restrict__ W, unsigned short* __restrict__ Wt,
                        int nmat, int K, int N) {
    int idx = blockIdx.x * 256 + threadIdx.x;
    int tot = nmat * K * N;
    if (idx >= tot) return;
    int m = idx / (K * N);
    int rem = idx - m * (K * N);
    int k = rem / N;
    int n = rem - k * N;
    Wt[(size_t)m * K * N + (size_t)n * K + k] = f2bf(W[idx]);
}

// ---------------- x fp32 -> bf16 ----------------
__global__ void xconv_k(const float* __restrict__ x, unsigned short* __restrict__ xb) {
    int idx = blockIdx.x * 256 + threadIdx.x;
    if (idx >= NN * DD / 4) return;
    float4 v = *reinterpret_cast<const float4*>(&x[(size_t)idx * 4]);
    ushort4 o;
    o.x = f2bf(v.x); o.y = f2bf(v.y); o.z = f2bf(v.z); o.w = f2bf(v.w);
    *reinterpret_cast<ushort4*>(&xb[(size_t)idx * 4]) = o;
}

// ---------------- MFMA bf16 GEMM: C[M][N] = A[M][K] @ Bt[N][K]^T (+bias) ----------------
// BM=BN=128, BK=32, 256 threads (4 waves, 2x2), 16x16x32 MFMA, global_load_lds staging.
__global__ __launch_bounds__(256) void gemm_mfma_k(const unsigned short* __restrict__ A,
                                                   const unsigned short* __restrict__ Bt,
                                                   const float* __restrict__ bias,
                                                   float* __restrict__ Cf,
                                                   unsigned short* __restrict__ Cb,
                                                   int M, int K, int N) {
    __shared__ __align__(16) short As[128 * 32];
    __shared__ __align__(16) short Bs[128 * 32];
    int bm = blockIdx.y * 128, bn = blockIdx.x * 128;
    int tid = threadIdx.x;
    int lane = tid & 63, w = tid >> 6;
    int wr = w >> 1, wc = w & 1;
    int l16 = lane & 15, kgrp = lane >> 4;
    f32x4 acc[4][4] = {};
    for (int k0 = 0; k0 < K; k0 += 32) {
        #pragma unroll
        for (int i = 0; i < 2; i++) {
            int chunk = (i * 4 + w) * 64 + lane;     // 0..511
            int row = chunk >> 2, kq = chunk & 3;
            int grow = bm + row; if (grow > M - 1) grow = M - 1;
            gload16(A + (size_t)grow * K + k0 + kq * 8, &As[(i * 4 + w) * 512]);
        }
        #pragma unroll
        for (int i = 0; i < 2; i++) {
            int chunk = (i * 4 + w) * 64 + lane;
            int row = chunk >> 2, kq = chunk & 3;
            gload16(Bt + (size_t)(bn + row) * K + k0 + kq * 8, &Bs[(i * 4 + w) * 512]);
        }
        __syncthreads();
        short8 af[4], bf[4];
        #pragma unroll
        for (int mi = 0; mi < 4; mi++) {
            int row = wr * 64 + mi * 16 + l16;
            af[mi] = *reinterpret_cast<const short8*>(&As[row * 32 + kgrp * 8]);
        }
        #pragma unroll
        for (int ni = 0; ni < 4; ni++) {
            int nrow = wc * 64 + ni * 16 + l16;
            bf[ni] = *reinterpret_cast<const short8*>(&Bs[nrow * 32 + kgrp * 8]);
        }
        #pragma unroll
        for (int mi = 0; mi < 4; mi++)
            #pragma unroll
            for (int ni = 0; ni < 4; ni++)
                acc[mi][ni] = __builtin_amdgcn_mfma_f32_16x16x32_bf16(af[mi], bf[ni], acc[mi][ni], 0, 0, 0);
        __syncthreads();
    }
    #pragma unroll
    for (int mi = 0; mi < 4; mi++) {
        #pragma unroll
        for (int r = 0; r < 4; r++) {
            int row = bm + wr * 64 + mi * 16 + (lane >> 4) * 4 + r;
            if (row < M) {
                #pragma unroll
                for (int ni = 0; ni < 4; ni++) {
                    int col = bn + wc * 64 + ni * 16 + l16;
                    float v = acc[mi][ni][r] + (bias ? bias[col] : 0.0f);
                    if (Cf) Cf[(size_t)row * N + col] = v;
                    if (Cb) Cb[(size_t)row * N + col] = f2bf(v);
                }
            }
        }
    }
}

// ---------------- LayerNorm + GELU, one wave per row of 256 ----------------
__global__ __launch_bounds__(256) void ln_gelu_k(const float* __restrict__ y,
                                                 const float* __restrict__ g,
                                                 const float* __restrict__ b,
                                                 float* __restrict__ outf,
                                                 unsigned short* __restrict__ outb) {
    int n = blockIdx.x * 4 + (threadIdx.x >> 6);
    int lane = threadIdx.x & 63;
    float4 v = *reinterpret_cast<const float4*>(&y[(size_t)n * HID + lane * 4]);
    float s = v.x + v.y + v.z + v.w;
    float q = v.x * v.x + v.y * v.y + v.z * v.z + v.w * v.w;
    #pragma unroll
    for (int o = 32; o; o >>= 1) { s += __shfl_xor(s, o); q += __shfl_xor(q, o); }
    float mean = s * (1.0f / HID);
    float var = q * (1.0f / HID) - mean * mean;
    float rs = rsqrtf(var + 1e-5f);
    float4 gv = *reinterpret_cast<const float4*>(&g[lane * 4]);
    float4 bv = *reinterpret_cast<const float4*>(&b[lane * 4]);
    float o0 = gelu_f(gv.x * (v.x - mean) * rs + bv.x);
    float o1 = gelu_f(gv.y * (v.y - mean) * rs + bv.y);
    float o2 = gelu_f(gv.z * (v.z - mean) * rs + bv.z);
    float o3 = gelu_f(gv.w * (v.w - mean) * rs + bv.w);
    if (outf) {
        float4 ov = {o0, o1, o2, o3};
        *reinterpret_cast<float4*>(&outf[(size_t)n * HID + lane * 4]) = ov;
    }
    ushort4 ob;
    ob.x = f2bf(o0); ob.y = f2bf(o1); ob.z = f2bf(o2); ob.w = f2bf(o3);
    *reinterpret_cast<ushort4*>(&outb[(size_t)n * HID + lane * 4]) = ob;
}

// ---------------- CSR build: batched over 3 edge types ----------------
__global__ void hist_k(const int* __restrict__ ei, int* __restrict__ cnt) {
    int gid = blockIdx.x * 256 + threadIdx.x;
    if (gid >= NT * EE) return;
    int t = gid / EE, e = gid - t * EE;
    int dst = ei[(size_t)t * 2 * EE + EE + e];
    atomicAdd(&cnt[t * NN + dst], 1);
}

__global__ __launch_bounds__(256) void scan1_k(const int* __restrict__ cnt, int* __restrict__ bsum, int n) {
    int i = blockIdx.x * 256 + threadIdx.x;
    int v = (i < n) ? cnt[i] : 0;
    #pragma unroll
    for (int o = 32; o; o >>= 1) v += __shfl_xor(v, o);
    __shared__ int s4[4];
    if ((threadIdx.x & 63) == 0) s4[threadIdx.x >> 6] = v;
    __syncthreads();
    if (threadIdx.x == 0) bsum[blockIdx.x] = s4[0] + s4[1] + s4[2] + s4[3];
}

__global__ __launch_bounds__(512) void scan2_k(const int* __restrict__ bsum, int* __restrict__ boff, int nb) {
    __shared__ int sh[512];
    int t = threadIdx.x;
    int v = (t < nb) ? bsum[t] : 0;
    sh[t] = v;
    __syncthreads();
    for (int o = 1; o < 512; o <<= 1) {
        int tv = (t >= o) ? sh[t - o] : 0;
        __syncthreads();
        sh[t] += tv;
        __syncthreads();
    }
    if (t < nb) boff[t] = sh[t] - v;
}

__global__ __launch_bounds__(256) void scan3_k(const int* __restrict__ cnt, const int* __restrict__ boff,
                                               int* __restrict__ roff, int n) {
    int i = blockIdx.x * 256 + threadIdx.x;
    int lane = threadIdx.x & 63, w = threadIdx.x >> 6;
    int v = (i < n) ? cnt[i] : 0;
    int s = v;
    #pragma unroll
    for (int o = 1; o < 64; o <<= 1) {
        int tv = __shfl_up(s, o);
        if (lane >= o) s += tv;
    }
    __shared__ int ws_[4];
    if (lane == 63) ws_[w] = s;
    __syncthreads();
    int add = 0;
    for (int k = 0; k < 4; k++) if (k < w) add += ws_[k];
    int incl = s + add + boff[blockIdx.x];
    if (i < n) roff[i] = incl - v;
    if (i == n - 1) roff[n] = incl;
}

__global__ void scatter_k(const int* __restrict__ ei, const float* __restrict__ ew,
                          const int* __restrict__ roff, int* __restrict__ cur,
                          int* __restrict__ csr_src, float* __restrict__ csr_ew) {
    int gid = blockIdx.x * 256 + threadIdx.x;
    if (gid >= NT * EE) return;
    int t = gid / EE, e = gid - t * EE;
    int src = ei[(size_t)t * 2 * EE + e];
    int dst = ei[(size_t)t * 2 * EE + EE + e];
    int pos = roff[t * NN + dst] + atomicAdd(&cur[t * NN + dst], 1);
    csr_src[pos] = src;
    csr_ew[pos] = ew[gid];
}

// ---------------- edge-weight gate from CSR ----------------
__global__ void ewg_kernel(const int* __restrict__ roff, const float* __restrict__ csr_ew,
                           float* __restrict__ ewg) {
    int n = blockIdx.x * 256 + threadIdx.x;
    if (n >= NN) return;
    float ws = 0.0f;
    int dg = 0;
    for (int t = 0; t < NT; t++) {
        int beg = roff[t * NN + n], end = roff[t * NN + n + 1];
        dg += end - beg;
        for (int e = beg; e < end; e++) ws += csr_ew[e];
    }
    float m = dg > 1 ? (float)dg : 1.0f;
    float z = ws / m;
    ewg[n] = 0.5f + 1.0f / (1.0f + __expf(-z));
}

// ---------------- per-(node,head) attention score inputs (bf16 xp, batched 3 types) -----
__global__ __launch_bounds__(256) void compute_s_k(const unsigned short* __restrict__ xp0,
                                                   const unsigned short* __restrict__ xp1,
                                                   const unsigned short* __restrict__ xp2,
                                                   const float* __restrict__ asrc,  // [3][256]
                                                   const float* __restrict__ adst,
                                                   float* __restrict__ ss,          // [3][NN][4]
                                                   float* __restrict__ sd) {
    int t = blockIdx.x / (NN / 4);
    int node = (blockIdx.x % (NN / 4)) * 4 + (threadIdx.x >> 6);
    int lane = threadIdx.x & 63;
    const unsigned short* xp = (t == 0) ? xp0 : (t == 1) ? xp1 : xp2;
    ushort4 v = *reinterpret_cast<const ushort4*>(&xp[(size_t)node * HID + lane * 4]);
    float4 av = *reinterpret_cast<const float4*>(&asrc[t * HID + lane * 4]);
    float4 dv = *reinterpret_cast<const float4*>(&adst[t * HID + lane * 4]);
    float x0 = bf2f(v.x), x1 = bf2f(v.y), x2 = bf2f(v.z), x3 = bf2f(v.w);
    float p = x0 * av.x + x1 * av.y + x2 * av.z + x3 * av.w;
    float q = x0 * dv.x + x1 * dv.y + x2 * dv.z + x3 * dv.w;
    #pragma unroll
    for (int o = 8; o; o >>= 1) { p += __shfl_xor(p, o); q += __shfl_xor(q, o); }
    if ((lane & 15) == 0) {
        ss[((size_t)t * NN + node) * NH + (lane >> 4)] = p;
        sd[((size_t)t * NN + node) * NH + (lane >> 4)] = q;
    }
}

// ---------------- fused layer: 3-type GAT agg + gate + ewg + residual + LN + GELU -------
__global__ __launch_bounds__(256) void layer_k(const unsigned short* __restrict__ xp0,
                                               const unsigned short* __restrict__ xp1,
                                               const unsigned short* __restrict__ xp2,
                                               const float* __restrict__ ss,
                                               const float* __restrict__ sd,
                                               const int* __restrict__ roff,
                                               const int* __restrict__ rsrc,
                                               const float* __restrict__ gatb,  // [3][256]
                                               const float* __restrict__ hin,
                                               const float* __restrict__ liq,
                                               const float* __restrict__ gW,    // [260]
                                               const float* __restrict__ gb,    // [1]
                                               const float* __restrict__ ewg,
                                               const float* __restrict__ lg,
                                               const float* __restrict__ lb,
                                               float* __restrict__ hout,
                                               unsigned short* __restrict__ houtb) {
    int node = blockIdx.x * 4 + (threadIdx.x >> 6);
    int lane = threadIdx.x & 63;
    int h = lane >> 4;
    float agg0 = 0, agg1 = 0, agg2 = 0, agg3 = 0;
    const unsigned short* xps[3] = {xp0, xp1, xp2};
    #pragma unroll
    for (int t = 0; t < NT; t++) {
        int beg = roff[t * NN + node], end = roff[t * NN + node + 1];
        if (beg == end) continue;
        float sdh = sd[((size_t)t * NN + node) * NH + h];
        float m = -1e30f;
        for (int e = beg; e < end; e++) {
            int s = rsrc[e];
            float sv = ss[((size_t)t * NN + s) * NH + h];
            m = fmaxf(m, lrelu_f(sv + sdh));
        }
        float den = 0, a0 = 0, a1 = 0, a2 = 0, a3 = 0;
        const unsigned short* xp = xps[t];
        for (int e = beg; e < end; e++) {
            int s = rsrc[e];
            float sv = ss[((size_t)t * NN + s) * NH + h];
            float wg = __expf(lrelu_f(sv + sdh) - m);
            den += wg;
            ushort4 xr = *reinterpret_cast<const ushort4*>(&xp[(size_t)s * HID + lane * 4]);
            a0 += wg * bf2f(xr.x);
            a1 += wg * bf2f(xr.y);
            a2 += wg * bf2f(xr.z);
            a3 += wg * bf2f(xr.w);
        }
        float inv = 1.0f / (den + 1e-16f);
        agg0 += a0 * inv; agg1 += a1 * inv; agg2 += a2 * inv; agg3 += a3 * inv;
    }
    float4 bb0 = *reinterpret_cast<const float4*>(&gatb[lane * 4]);
    float4 bb1 = *reinterpret_cast<const float4*>(&gatb[HID + lane * 4]);
    float4 bb2 = *reinterpret_cast<const float4*>(&gatb[2 * HID + lane * 4]);
    agg0 += bb0.x + bb1.x + bb2.x;
    agg1 += bb0.y + bb1.y + bb2.y;
    agg2 += bb0.z + bb1.z + bb2.z;
    agg3 += bb0.w + bb1.w + bb2.w;
    // gate logit
    float4 gwv = *reinterpret_cast<const float4*>(&gW[lane * 4]);
    float part = agg0 * gwv.x + agg1 * gwv.y + agg2 * gwv.z + agg3 * gwv.w;
    if (lane < 4) part += liq[node * 4 + lane] * gW[HID + lane];
    #pragma unroll
    for (int o = 32; o; o >>= 1) part += __shfl_xor(part, o);
    float gate = 1.0f / (1.0f + __expf(-(part + gb[0])));
    float eg = ewg[node];
    float4 hh = *reinterpret_cast<const float4*>(&hin[(size_t)node * HID + lane * 4]);
    float v0 = (gate * agg0 + (1.0f - gate) * hh.x) * eg + hh.x;
    float v1 = (gate * agg1 + (1.0f - gate) * hh.y) * eg + hh.y;
    float v2 = (gate * agg2 + (1.0f - gate) * hh.z) * eg + hh.z;
    float v3 = (gate * agg3 + (1.0f - gate) * hh.w) * eg + hh.w;
    float s = v0 + v1 + v2 + v3;
    float q = v0 * v0 + v1 * v1 + v2 * v2 + v3 * v3;
    #pragma unroll
    for (int o = 32; o; o >>= 1) { s += __shfl_xor(s, o); q += __shfl_xor(q, o); }
    float mean = s * (1.0f / HID);
    float var = q * (1.0f / HID) - mean * mean;
    float rs = rsqrtf(var + 1e-5f);
    float4 lgv = *reinterpret_cast<const float4*>(&lg[lane * 4]);
    float4 lbv = *reinterpret_cast<const float4*>(&lb[lane * 4]);
    float o0 = gelu_f(lgv.x * (v0 - mean) * rs + lbv.x);
    float o1 = gelu_f(lgv.y * (v1 - mean) * rs + lbv.y);
    float o2 = gelu_f(lgv.z * (v2 - mean) * rs + lbv.z);
    float o3 = gelu_f(lgv.w * (v3 - mean) * rs + lbv.w);
    float4 ov = {o0, o1, o2, o3};
    *reinterpret_cast<float4*>(&hout[(size_t)node * HID + lane * 4]) = ov;
    ushort4 ob;
    ob.x = f2bf(o0); ob.y = f2bf(o1); ob.z = f2bf(o2); ob.w = f2bf(o3);
    *reinterpret_cast<ushort4*>(&houtb[(size_t)node * HID + lane * 4]) = ob;
}

// ---------------- column partial sums of ho (N x D) ----------------
__global__ __launch_bounds__(128) void colpart_k(const float* __restrict__ ho,
                                                 float* __restrict__ part) {
    int c = threadIdx.x, b = blockIdx.x;
    float s = 0.0f;
    for (int r = b; r < NN; r += 256) s += ho[(size_t)r * DD + c];
    part[b * DD + c] = s;
}

// ---------------- readout MLP (single block) ----------------
__global__ __launch_bounds__(256) void readout_k(const float* __restrict__ part,
                                                 const float* __restrict__ W1,
                                                 const float* __restrict__ b1,
                                                 const float* __restrict__ W2,
                                                 const float* __restrict__ b2,
                                                 float* __restrict__ surf) {
    __shared__ float m[DD];
    __shared__ float a1[HID];
    int t = threadIdx.x;
    if (t < DD) {
        float s = 0.0f;
        for (int b = 0; b < 256; b++) s += part[b * DD + t];
        m[t] = s / (float)NN;
    }
    __syncthreads();
    float s1 = b1[t];
    for (int k = 0; k < DD; k++) s1 += m[k] * W1[k * HID + t];
    a1[t] = gelu_f(s1);
    __syncthreads();
    float s2 = b2[t];
    for (int k = 0; k < HID; k++) s2 += a1[k] * W2[k * HID + t];
    surf[t] = s2;
}

extern "C" void kernel_launch(void* const* d_in, const int* in_sizes, int n_in,
                              void* d_out, int out_size, void* d_ws, size_t ws_size,
                              hipStream_t stream) {
    const float* x       = (const float*)d_in[0];
    const float* liq     = (const float*)d_in[1];
    const int*   ei      = (const int*)d_in[2];
    const float* ew      = (const float*)d_in[3];
    const float* in_W    = (const float*)d_in[4];
    const float* in_b    = (const float*)d_in[5];
    const float* in_g    = (const float*)d_in[6];
    const float* in_bb   = (const float*)d_in[7];
    const float* gat_W   = (const float*)d_in[8];
    const float* gat_as  = (const float*)d_in[9];
    const float* gat_ad  = (const float*)d_in[10];
    const float* gat_b   = (const float*)d_in[11];
    const float* ln_g    = (const float*)d_in[12];
    const float* ln_b    = (const float*)d_in[13];
    const float* gate_W  = (const float*)d_in[14];
    const float* gate_b  = (const float*)d_in[15];
    const float* out_W1  = (const float*)d_in[16];
    const float* out_b1  = (const float*)d_in[17];
    const float* out_g   = (const float*)d_in[18];
    const float* out_bb  = (const float*)d_in[19];
    const float* out_W2  = (const float*)d_in[20];
    const float* out_b2  = (const float*)d_in[21];
    const float* ro_W1   = (const float*)d_in[22];
    const float* ro_b1   = (const float*)d_in[23];
    const float* ro_W2   = (const float*)d_in[24];
    const float* ro_b2   = (const float*)d_in[25];

    float* out = (float*)d_out;
    float* out_ho   = out;
    float* out_surf = out + (size_t)NN * DD;
    float* out_h[3];
    out_h[0] = out_surf + HID;
    out_h[1] = out_h[0] + (size_t)NN * HID;
    out_h[2] = out_h[1] + (size_t)NN * HID;

    char* wsb = (char*)d_ws;
    size_t off = 0;
    auto alloc = [&](size_t bytes) { char* p = wsb + off; off += (bytes + 255) & ~(size_t)255; return p; };
    // xp0..xp2: bf16 per-type projections. Cf32 (fp32 GEMM out, 41MB) aliases xp0+xp1.
    // xb (bf16 x, 10.2MB) aliases the front of xp2 (dead once GEMM-1 completes; xp2
    // first written in layer 0 after that).
    unsigned short* xp0 = (unsigned short*)alloc((size_t)NN * HID * 2);
    unsigned short* xp1 = (unsigned short*)alloc((size_t)NN * HID * 2);
    unsigned short* xp2 = (unsigned short*)alloc((size_t)NN * HID * 2);
    float* Cf32 = (float*)xp0;               // alias (xp0+xp1 = exactly NN*HID floats)
    unsigned short* xb = xp2;                // alias (NN*DD bf16 fits in xp2)
    unsigned short* hb = (unsigned short*)alloc((size_t)NN * HID * 2);  // single bf16 h shadow
    unsigned short* Wt_in  = (unsigned short*)alloc((size_t)DD * HID * 2);
    unsigned short* Wt_gat = (unsigned short*)alloc((size_t)LL * NT * HID * HID * 2);
    unsigned short* Wt_o1  = (unsigned short*)alloc((size_t)HID * HID * 2);
    unsigned short* Wt_o2  = (unsigned short*)alloc((size_t)HID * DD * 2);
    // Region R: CSR scratch {cew, cnt, bsum, boff} then reused as {ss, sd} in layers.
    size_t cew_b = (size_t)NT * EE * 4;           // 3.84 MB
    size_t cnt_b = (size_t)NT * NN * 4;           // 0.48 MB
    char* R = alloc(cew_b + cnt_b + 2 * 2048 * 4);
    float* cew = (float*)R;
    int* cnt   = (int*)(R + cew_b);
    int* bsum  = (int*)(R + cew_b + cnt_b);
    int* boff  = bsum + 2048;
    float* ss  = (float*)R;                       // alias: live only after ewg_kernel
    float* sd  = ss + (size_t)NT * NN * NH;
    int* roff  = (int*)alloc(((size_t)NT * NN + 1) * 4);
    int* rsrc  = (int*)alloc((size_t)NT * EE * 4);
    float* ewg = (float*)alloc((size_t)NN * 4);
    float* cpart = (float*)alloc((size_t)256 * DD * 4);

    const int NSC = (NT * NN + 255) / 256;  // 469 scan blocks

    // ---- weight conversions (bf16, transposed to [N][K]) ----
    wconv_k<<<(DD * HID + 255) / 256, 256, 0, stream>>>(in_W, Wt_in, 1, DD, HID);
    wconv_k<<<(LL * NT * HID * HID + 255) / 256, 256, 0, stream>>>(gat_W, Wt_gat, LL * NT, HID, HID);
    wconv_k<<<(HID * HID + 255) / 256, 256, 0, stream>>>(out_W1, Wt_o1, 1, HID, HID);
    wconv_k<<<(HID * DD + 255) / 256, 256, 0, stream>>>(out_W2, Wt_o2, 1, HID, DD);
    xconv_k<<<(NN * DD / 4 + 255) / 256, 256, 0, stream>>>(x, xb);

    // ---- input projection + LN + GELU -> h0 (fp32 in h-slot of d_out, bf16 in hb) ----
    // (runs before CSR build so xb [aliasing xp2] is dead before R/cew is used)
    gemm_mfma_k<<<dim3(HID / 128, (NN + 127) / 128), 256, 0, stream>>>(
        xb, Wt_in, in_b, Cf32, nullptr, NN, DD, HID);
    ln_gelu_k<<<NN / 4, 256, 0, stream>>>(Cf32, in_g, in_bb, out_h[0], hb);

    // ---- CSR build (batched, all 3 types) ----
    hipMemsetAsync(cnt, 0, cnt_b, stream);
    hist_k<<<(NT * EE + 255) / 256, 256, 0, stream>>>(ei, cnt);
    scan1_k<<<NSC, 256, 0, stream>>>(cnt, bsum, NT * NN);
    scan2_k<<<1, 512, 0, stream>>>(bsum, boff, NSC);
    scan3_k<<<NSC, 256, 0, stream>>>(cnt, boff, roff, NT * NN);
    hipMemsetAsync(cnt, 0, cnt_b, stream);
    scatter_k<<<(NT * EE + 255) / 256, 256, 0, stream>>>(ei, ew, roff, cnt, rsrc, cew);
    ewg_kernel<<<(NN + 255) / 256, 256, 0, stream>>>(roff, cew, ewg);

    // ---- message-passing layers ----
    const float* hin_f = out_h[0];
    for (int i = 0; i < LL; i++) {
        for (int t = 0; t < NT; t++) {
            int wi = i * NT + t;
            unsigned short* xpt = (t == 0) ? xp0 : (t == 1) ? xp1 : xp2;
            gemm_mfma_k<<<dim3(HID / 128, (NN + 127) / 128), 256, 0, stream>>>(
                hb, Wt_gat + (size_t)wi * HID * HID, nullptr, nullptr, xpt, NN, HID, HID);
        }
        compute_s_k<<<NT * (NN / 4), 256, 0, stream>>>(
            xp0, xp1, xp2, gat_as + (size_t)i * NT * HID, gat_ad + (size_t)i * NT * HID, ss, sd);
        layer_k<<<NN / 4, 256, 0, stream>>>(
            xp0, xp1, xp2, ss, sd, roff, rsrc, gat_b + (size_t)i * NT * HID,
            hin_f, liq, gate_W, gate_b, ewg, ln_g + i * HID, ln_b + i * HID,
            out_h[i], hb);   // hb overwritten in place (GEMMs of this layer already done)
        hin_f = out_h[i];
    }

    // ---- output head ----
    gemm_mfma_k<<<dim3(HID / 128, (NN + 127) / 128), 256, 0, stream>>>(
        hb, Wt_o1, out_b1, Cf32, nullptr, NN, HID, HID);
    ln_gelu_k<<<NN / 4, 256, 0, stream>>>(Cf32, out_g, out_bb, nullptr, hb);
    gemm_mfma_k<<<dim3(DD / 128, (NN + 127) / 128), 256, 0, stream>>>(
        hb, Wt_o2, out_b2, out_ho, nullptr, NN, HID, DD);

    // ---- readout ----
    colpart_k<<<256, 128, 0, stream>>>(out_ho, cpart);
    readout_k<<<1, 256, 0, stream>>>(cpart, ro_W1, ro_b1, ro_W2, ro_b2, out_surf);
}

// Round 4
// 851.183 us; speedup vs baseline: 3.2980x; 1.2347x over previous
//
#include <hip/hip_runtime.h>
#include <hip/hip_bf16.h>
#include <math.h>

#define NN 40000
#define EE 320000
#define NT 3
#define LL 3
#define DD 128
#define HID 256
#define NH 4
#define CC 64
#define NP 768   // NT*HID: batched projection width

typedef __attribute__((ext_vector_type(8))) short short8;
typedef __attribute__((ext_vector_type(4))) float f32x4;

__device__ __forceinline__ float gelu_f(float x) {
    return 0.5f * x * (1.0f + erff(x * 0.70710678118654752440f));
}
__device__ __forceinline__ float lrelu_f(float x) {
    return x > 0.0f ? x : 0.2f * x;
}
__device__ __forceinline__ float bf2f(unsigned short u) {
    unsigned int x = ((unsigned int)u) << 16;
    float f;
    __builtin_memcpy(&f, &x, 4);
    return f;
}
__device__ __forceinline__ unsigned short f2bf(float f) {
    __hip_bfloat16 h = __float2bfloat16(f);
    unsigned short u;
    __builtin_memcpy(&u, &h, 2);
    return u;
}
__device__ __forceinline__ void gload16(const void* g, void* l) {
    __builtin_amdgcn_global_load_lds(
        (const __attribute__((address_space(1))) unsigned int*)g,
        (__attribute__((address_space(3))) unsigned int*)l, 16, 0, 0);
}

// ---------------- weight transpose + bf16 convert: W[m][K][N] -> Wt[m][N][K] ----------------
__global__ void wconv_k(const float* __restrict__ W, unsigned short* __restrict__ Wt,
                        int nmat, int K, int N) {
    int idx = blockIdx.x * 256 + threadIdx.x;
    int tot = nmat * K * N;
    if (idx >= tot) return;
    int m = idx / (K * N);
    int rem = idx - m * (K * N);
    int k = rem / N;
    int n = rem - k * N;
    Wt[(size_t)m * K * N + (size_t)n * K + k] = f2bf(W[idx]);
}

// ---------------- x fp32 -> bf16 ----------------
__global__ void xconv_k(const float* __restrict__ x, unsigned short* __restrict__ xb) {
    int idx = blockIdx.x * 256 + threadIdx.x;
    if (idx >= NN * DD / 4) return;
    float4 v = *reinterpret_cast<const float4*>(&x[(size_t)idx * 4]);
    ushort4 o;
    o.x = f2bf(v.x); o.y = f2bf(v.y); o.z = f2bf(v.z); o.w = f2bf(v.w);
    *reinterpret_cast<ushort4*>(&xb[(size_t)idx * 4]) = o;
}

// ---------------- MFMA bf16 GEMM: C[M][N] = A[M][K] @ Bt[N][K]^T (+bias) ----------------
// BM=BN=128, BK=32, 256 threads (4 waves, 2x2), 16x16x32 MFMA, global_load_lds staging.
__global__ __launch_bounds__(256) void gemm_mfma_k(const unsigned short* __restrict__ A,
                                                   const unsigned short* __restrict__ Bt,
                                                   const float* __restrict__ bias,
                                                   float* __restrict__ Cf,
                                                   unsigned short* __restrict__ Cb,
                                                   int M, int K, int N) {
    __shared__ __align__(16) short As[128 * 32];
    __shared__ __align__(16) short Bs[128 * 32];
    int bm = blockIdx.y * 128, bn = blockIdx.x * 128;
    int tid = threadIdx.x;
    int lane = tid & 63, w = tid >> 6;
    int wr = w >> 1, wc = w & 1;
    int l16 = lane & 15, kgrp = lane >> 4;
    f32x4 acc[4][4] = {};
    for (int k0 = 0; k0 < K; k0 += 32) {
        #pragma unroll
        for (int i = 0; i < 2; i++) {
            int chunk = (i * 4 + w) * 64 + lane;     // 0..511
            int row = chunk >> 2, kq = chunk & 3;
            int grow = bm + row; if (grow > M - 1) grow = M - 1;
            gload16(A + (size_t)grow * K + k0 + kq * 8, &As[(i * 4 + w) * 512]);
        }
        #pragma unroll
        for (int i = 0; i < 2; i++) {
            int chunk = (i * 4 + w) * 64 + lane;
            int row = chunk >> 2, kq = chunk & 3;
            gload16(Bt + (size_t)(bn + row) * K + k0 + kq * 8, &Bs[(i * 4 + w) * 512]);
        }
        __syncthreads();
        short8 af[4], bf[4];
        #pragma unroll
        for (int mi = 0; mi < 4; mi++) {
            int row = wr * 64 + mi * 16 + l16;
            af[mi] = *reinterpret_cast<const short8*>(&As[row * 32 + kgrp * 8]);
        }
        #pragma unroll
        for (int ni = 0; ni < 4; ni++) {
            int nrow = wc * 64 + ni * 16 + l16;
            bf[ni] = *reinterpret_cast<const short8*>(&Bs[nrow * 32 + kgrp * 8]);
        }
        #pragma unroll
        for (int mi = 0; mi < 4; mi++)
            #pragma unroll
            for (int ni = 0; ni < 4; ni++)
                acc[mi][ni] = __builtin_amdgcn_mfma_f32_16x16x32_bf16(af[mi], bf[ni], acc[mi][ni], 0, 0, 0);
        __syncthreads();
    }
    #pragma unroll
    for (int mi = 0; mi < 4; mi++) {
        #pragma unroll
        for (int r = 0; r < 4; r++) {
            int row = bm + wr * 64 + mi * 16 + (lane >> 4) * 4 + r;
            if (row < M) {
                #pragma unroll
                for (int ni = 0; ni < 4; ni++) {
                    int col = bn + wc * 64 + ni * 16 + l16;
                    float v = acc[mi][ni][r] + (bias ? bias[col] : 0.0f);
                    if (Cf) Cf[(size_t)row * N + col] = v;
                    if (Cb) Cb[(size_t)row * N + col] = f2bf(v);
                }
            }
        }
    }
}

// ---------------- LayerNorm + GELU, one wave per row of 256 ----------------
__global__ __launch_bounds__(256) void ln_gelu_k(const float* __restrict__ y,
                                                 const float* __restrict__ g,
                                                 const float* __restrict__ b,
                                                 float* __restrict__ outf,
                                                 unsigned short* __restrict__ outb) {
    int n = blockIdx.x * 4 + (threadIdx.x >> 6);
    int lane = threadIdx.x & 63;
    float4 v = *reinterpret_cast<const float4*>(&y[(size_t)n * HID + lane * 4]);
    float s = v.x + v.y + v.z + v.w;
    float q = v.x * v.x + v.y * v.y + v.z * v.z + v.w * v.w;
    #pragma unroll
    for (int o = 32; o; o >>= 1) { s += __shfl_xor(s, o); q += __shfl_xor(q, o); }
    float mean = s * (1.0f / HID);
    float var = q * (1.0f / HID) - mean * mean;
    float rs = rsqrtf(var + 1e-5f);
    float4 gv = *reinterpret_cast<const float4*>(&g[lane * 4]);
    float4 bv = *reinterpret_cast<const float4*>(&b[lane * 4]);
    float o0 = gelu_f(gv.x * (v.x - mean) * rs + bv.x);
    float o1 = gelu_f(gv.y * (v.y - mean) * rs + bv.y);
    float o2 = gelu_f(gv.z * (v.z - mean) * rs + bv.z);
    float o3 = gelu_f(gv.w * (v.w - mean) * rs + bv.w);
    if (outf) {
        float4 ov = {o0, o1, o2, o3};
        *reinterpret_cast<float4*>(&outf[(size_t)n * HID + lane * 4]) = ov;
    }
    ushort4 ob;
    ob.x = f2bf(o0); ob.y = f2bf(o1); ob.z = f2bf(o2); ob.w = f2bf(o3);
    *reinterpret_cast<ushort4*>(&outb[(size_t)n * HID + lane * 4]) = ob;
}

// ---------------- CSR build: batched over 3 edge types ----------------
__global__ void hist_k(const int* __restrict__ ei, int* __restrict__ cnt) {
    int gid = blockIdx.x * 256 + threadIdx.x;
    if (gid >= NT * EE) return;
    int t = gid / EE, e = gid - t * EE;
    int dst = ei[(size_t)t * 2 * EE + EE + e];
    atomicAdd(&cnt[t * NN + dst], 1);
}

__global__ __launch_bounds__(256) void scan1_k(const int* __restrict__ cnt, int* __restrict__ bsum, int n) {
    int i = blockIdx.x * 256 + threadIdx.x;
    int v = (i < n) ? cnt[i] : 0;
    #pragma unroll
    for (int o = 32; o; o >>= 1) v += __shfl_xor(v, o);
    __shared__ int s4[4];
    if ((threadIdx.x & 63) == 0) s4[threadIdx.x >> 6] = v;
    __syncthreads();
    if (threadIdx.x == 0) bsum[blockIdx.x] = s4[0] + s4[1] + s4[2] + s4[3];
}

__global__ __launch_bounds__(512) void scan2_k(const int* __restrict__ bsum, int* __restrict__ boff, int nb) {
    __shared__ int sh[512];
    int t = threadIdx.x;
    int v = (t < nb) ? bsum[t] : 0;
    sh[t] = v;
    __syncthreads();
    for (int o = 1; o < 512; o <<= 1) {
        int tv = (t >= o) ? sh[t - o] : 0;
        __syncthreads();
        sh[t] += tv;
        __syncthreads();
    }
    if (t < nb) boff[t] = sh[t] - v;
}

__global__ __launch_bounds__(256) void scan3_k(const int* __restrict__ cnt, const int* __restrict__ boff,
                                               int* __restrict__ roff, int n) {
    int i = blockIdx.x * 256 + threadIdx.x;
    int lane = threadIdx.x & 63, w = threadIdx.x >> 6;
    int v = (i < n) ? cnt[i] : 0;
    int s = v;
    #pragma unroll
    for (int o = 1; o < 64; o <<= 1) {
        int tv = __shfl_up(s, o);
        if (lane >= o) s += tv;
    }
    __shared__ int ws_[4];
    if (lane == 63) ws_[w] = s;
    __syncthreads();
    int add = 0;
    for (int k = 0; k < 4; k++) if (k < w) add += ws_[k];
    int incl = s + add + boff[blockIdx.x];
    if (i < n) roff[i] = incl - v;
    if (i == n - 1) roff[n] = incl;
}

__global__ void scatter_k(const int* __restrict__ ei, const float* __restrict__ ew,
                          const int* __restrict__ roff, int* __restrict__ cur,
                          int* __restrict__ csr_src, float* __restrict__ csr_ew) {
    int gid = blockIdx.x * 256 + threadIdx.x;
    if (gid >= NT * EE) return;
    int t = gid / EE, e = gid - t * EE;
    int src = ei[(size_t)t * 2 * EE + e];
    int dst = ei[(size_t)t * 2 * EE + EE + e];
    int pos = roff[t * NN + dst] + atomicAdd(&cur[t * NN + dst], 1);
    csr_src[pos] = src;
    csr_ew[pos] = ew[gid];
}

// ---------------- edge-weight gate from CSR ----------------
__global__ void ewg_kernel(const int* __restrict__ roff, const float* __restrict__ csr_ew,
                           float* __restrict__ ewg) {
    int n = blockIdx.x * 256 + threadIdx.x;
    if (n >= NN) return;
    float ws = 0.0f;
    int dg = 0;
    for (int t = 0; t < NT; t++) {
        int beg = roff[t * NN + n], end = roff[t * NN + n + 1];
        dg += end - beg;
        for (int e = beg; e < end; e++) ws += csr_ew[e];
    }
    float m = dg > 1 ? (float)dg : 1.0f;
    float z = ws / m;
    ewg[n] = 0.5f + 1.0f / (1.0f + __expf(-z));
}

// ---------------- per-(node,head) attention score inputs (bf16 xpa [NN][768]) -----
__global__ __launch_bounds__(256) void compute_s_k(const unsigned short* __restrict__ xpa,
                                                   const float* __restrict__ asrc,  // [3][256]
                                                   const float* __restrict__ adst,
                                                   float* __restrict__ ss,          // [3][NN][4]
                                                   float* __restrict__ sd) {
    int t = blockIdx.x / (NN / 4);
    int node = (blockIdx.x % (NN / 4)) * 4 + (threadIdx.x >> 6);
    int lane = threadIdx.x & 63;
    ushort4 v = *reinterpret_cast<const ushort4*>(&xpa[(size_t)node * NP + t * HID + lane * 4]);
    float4 av = *reinterpret_cast<const float4*>(&asrc[t * HID + lane * 4]);
    float4 dv = *reinterpret_cast<const float4*>(&adst[t * HID + lane * 4]);
    float x0 = bf2f(v.x), x1 = bf2f(v.y), x2 = bf2f(v.z), x3 = bf2f(v.w);
    float p = x0 * av.x + x1 * av.y + x2 * av.z + x3 * av.w;
    float q = x0 * dv.x + x1 * dv.y + x2 * dv.z + x3 * dv.w;
    #pragma unroll
    for (int o = 8; o; o >>= 1) { p += __shfl_xor(p, o); q += __shfl_xor(q, o); }
    if ((lane & 15) == 0) {
        ss[((size_t)t * NN + node) * NH + (lane >> 4)] = p;
        sd[((size_t)t * NN + node) * NH + (lane >> 4)] = q;
    }
}

// ---- fused layer: 3-type GAT agg (online softmax, 1 pass) + gate + ewg + res + LN + GELU
__global__ __launch_bounds__(256) void layer_k(const unsigned short* __restrict__ xpa, // [NN][768]
                                               const float* __restrict__ ss,
                                               const float* __restrict__ sd,
                                               const int* __restrict__ roff,
                                               const int* __restrict__ rsrc,
                                               const float* __restrict__ gatb,  // [3][256]
                                               const float* __restrict__ hin,
                                               const float* __restrict__ liq,
                                               const float* __restrict__ gW,    // [260]
                                               const float* __restrict__ gb,    // [1]
                                               const float* __restrict__ ewg,
                                               const float* __restrict__ lg,
                                               const float* __restrict__ lb,
                                               float* __restrict__ hout,
                                               unsigned short* __restrict__ houtb) {
    int node = blockIdx.x * 4 + (threadIdx.x >> 6);
    int lane = threadIdx.x & 63;
    int h = lane >> 4;
    float agg0 = 0, agg1 = 0, agg2 = 0, agg3 = 0;
    #pragma unroll
    for (int t = 0; t < NT; t++) {
        int beg = roff[t * NN + node], end = roff[t * NN + node + 1];
        if (beg == end) continue;
        float sdh = sd[((size_t)t * NN + node) * NH + h];
        float m = -1e30f, den = 0, a0 = 0, a1 = 0, a2 = 0, a3 = 0;
        // software pipeline: prefetch edge e+1 while accumulating edge e
        int s_n = rsrc[beg];
        float sv_n = ss[((size_t)t * NN + s_n) * NH + h];
        ushort4 xr_n = *reinterpret_cast<const ushort4*>(&xpa[(size_t)s_n * NP + t * HID + lane * 4]);
        for (int e = beg; e < end; e++) {
            float sv_c = sv_n;
            ushort4 xr_c = xr_n;
            if (e + 1 < end) {
                int sn = rsrc[e + 1];
                sv_n = ss[((size_t)t * NN + sn) * NH + h];
                xr_n = *reinterpret_cast<const ushort4*>(&xpa[(size_t)sn * NP + t * HID + lane * 4]);
            }
            float sc = lrelu_f(sv_c + sdh);
            float wg;
            if (sc > m) {
                float r = __expf(m - sc);   // first iter: exp(-huge)=0
                den *= r; a0 *= r; a1 *= r; a2 *= r; a3 *= r;
                m = sc;
                wg = 1.0f;
            } else {
                wg = __expf(sc - m);
            }
            den += wg;
            a0 += wg * bf2f(xr_c.x);
            a1 += wg * bf2f(xr_c.y);
            a2 += wg * bf2f(xr_c.z);
            a3 += wg * bf2f(xr_c.w);
        }
        float inv = 1.0f / (den + 1e-16f);
        agg0 += a0 * inv; agg1 += a1 * inv; agg2 += a2 * inv; agg3 += a3 * inv;
    }
    float4 bb0 = *reinterpret_cast<const float4*>(&gatb[lane * 4]);
    float4 bb1 = *reinterpret_cast<const float4*>(&gatb[HID + lane * 4]);
    float4 bb2 = *reinterpret_cast<const float4*>(&gatb[2 * HID + lane * 4]);
    agg0 += bb0.x + bb1.x + bb2.x;
    agg1 += bb0.y + bb1.y + bb2.y;
    agg2 += bb0.z + bb1.z + bb2.z;
    agg3 += bb0.w + bb1.w + bb2.w;
    // gate logit
    float4 gwv = *reinterpret_cast<const float4*>(&gW[lane * 4]);
    float part = agg0 * gwv.x + agg1 * gwv.y + agg2 * gwv.z + agg3 * gwv.w;
    if (lane < 4) part += liq[node * 4 + lane] * gW[HID + lane];
    #pragma unroll
    for (int o = 32; o; o >>= 1) part += __shfl_xor(part, o);
    float gate = 1.0f / (1.0f + __expf(-(part + gb[0])));
    float eg = ewg[node];
    float4 hh = *reinterpret_cast<const float4*>(&hin[(size_t)node * HID + lane * 4]);
    float v0 = (gate * agg0 + (1.0f - gate) * hh.x) * eg + hh.x;
    float v1 = (gate * agg1 + (1.0f - gate) * hh.y) * eg + hh.y;
    float v2 = (gate * agg2 + (1.0f - gate) * hh.z) * eg + hh.z;
    float v3 = (gate * agg3 + (1.0f - gate) * hh.w) * eg + hh.w;
    float s = v0 + v1 + v2 + v3;
    float q = v0 * v0 + v1 * v1 + v2 * v2 + v3 * v3;
    #pragma unroll
    for (int o = 32; o; o >>= 1) { s += __shfl_xor(s, o); q += __shfl_xor(q, o); }
    float mean = s * (1.0f / HID);
    float var = q * (1.0f / HID) - mean * mean;
    float rs = rsqrtf(var + 1e-5f);
    float4 lgv = *reinterpret_cast<const float4*>(&lg[lane * 4]);
    float4 lbv = *reinterpret_cast<const float4*>(&lb[lane * 4]);
    float o0 = gelu_f(lgv.x * (v0 - mean) * rs + lbv.x);
    float o1 = gelu_f(lgv.y * (v1 - mean) * rs + lbv.y);
    float o2 = gelu_f(lgv.z * (v2 - mean) * rs + lbv.z);
    float o3 = gelu_f(lgv.w * (v3 - mean) * rs + lbv.w);
    float4 ov = {o0, o1, o2, o3};
    *reinterpret_cast<float4*>(&hout[(size_t)node * HID + lane * 4]) = ov;
    ushort4 ob;
    ob.x = f2bf(o0); ob.y = f2bf(o1); ob.z = f2bf(o2); ob.w = f2bf(o3);
    *reinterpret_cast<ushort4*>(&houtb[(size_t)node * HID + lane * 4]) = ob;
}

// ---------------- column partial sums of ho (N x D) ----------------
__global__ __launch_bounds__(128) void colpart_k(const float* __restrict__ ho,
                                                 float* __restrict__ part) {
    int c = threadIdx.x, b = blockIdx.x;
    float s = 0.0f;
    for (int r = b; r < NN; r += 256) s += ho[(size_t)r * DD + c];
    part[b * DD + c] = s;
}

// ---------------- readout MLP (single block) ----------------
__global__ __launch_bounds__(256) void readout_k(const float* __restrict__ part,
                                                 const float* __restrict__ W1,
                                                 const float* __restrict__ b1,
                                                 const float* __restrict__ W2,
                                                 const float* __restrict__ b2,
                                                 float* __restrict__ surf) {
    __shared__ float m[DD];
    __shared__ float a1[HID];
    int t = threadIdx.x;
    if (t < DD) {
        float s = 0.0f;
        for (int b = 0; b < 256; b++) s += part[b * DD + t];
        m[t] = s / (float)NN;
    }
    __syncthreads();
    float s1 = b1[t];
    for (int k = 0; k < DD; k++) s1 += m[k] * W1[k * HID + t];
    a1[t] = gelu_f(s1);
    __syncthreads();
    float s2 = b2[t];
    for (int k = 0; k < HID; k++) s2 += a1[k] * W2[k * HID + t];
    surf[t] = s2;
}

extern "C" void kernel_launch(void* const* d_in, const int* in_sizes, int n_in,
                              void* d_out, int out_size, void* d_ws, size_t ws_size,
                              hipStream_t stream) {
    const float* x       = (const float*)d_in[0];
    const float* liq     = (const float*)d_in[1];
    const int*   ei      = (const int*)d_in[2];
    const float* ew      = (const float*)d_in[3];
    const float* in_W    = (const float*)d_in[4];
    const float* in_b    = (const float*)d_in[5];
    const float* in_g    = (const float*)d_in[6];
    const float* in_bb   = (const float*)d_in[7];
    const float* gat_W   = (const float*)d_in[8];
    const float* gat_as  = (const float*)d_in[9];
    const float* gat_ad  = (const float*)d_in[10];
    const float* gat_b   = (const float*)d_in[11];
    const float* ln_g    = (const float*)d_in[12];
    const float* ln_b    = (const float*)d_in[13];
    const float* gate_W  = (const float*)d_in[14];
    const float* gate_b  = (const float*)d_in[15];
    const float* out_W1  = (const float*)d_in[16];
    const float* out_b1  = (const float*)d_in[17];
    const float* out_g   = (const float*)d_in[18];
    const float* out_bb  = (const float*)d_in[19];
    const float* out_W2  = (const float*)d_in[20];
    const float* out_b2  = (const float*)d_in[21];
    const float* ro_W1   = (const float*)d_in[22];
    const float* ro_b1   = (const float*)d_in[23];
    const float* ro_W2   = (const float*)d_in[24];
    const float* ro_b2   = (const float*)d_in[25];

    float* out = (float*)d_out;
    float* out_ho   = out;
    float* out_surf = out + (size_t)NN * DD;
    float* out_h[3];
    out_h[0] = out_surf + HID;
    out_h[1] = out_h[0] + (size_t)NN * HID;
    out_h[2] = out_h[1] + (size_t)NN * HID;

    char* wsb = (char*)d_ws;
    size_t off = 0;
    auto alloc = [&](size_t bytes) { char* p = wsb + off; off += (bytes + 255) & ~(size_t)255; return p; };
    // xpa: bf16 batched projections [NN][768]. Aliases inside it:
    //   Cf32 (fp32 GEMM out, NN*256 f32 = NN*512 ushorts) at the front,
    //   xb (bf16 x, NN*128 ushorts) right after Cf32 — both dead before layer 0's GEMM
    //   overwrites xpa.
    unsigned short* xpa = (unsigned short*)alloc((size_t)NN * NP * 2);
    float* Cf32 = (float*)xpa;
    unsigned short* xb = xpa + (size_t)NN * 512;
    unsigned short* hb = (unsigned short*)alloc((size_t)NN * HID * 2);  // bf16 h shadow
    unsigned short* Wt_in  = (unsigned short*)alloc((size_t)DD * HID * 2);
    unsigned short* Wt_gat = (unsigned short*)alloc((size_t)LL * NT * HID * HID * 2); // [L][768][256]
    unsigned short* Wt_o1  = (unsigned short*)alloc((size_t)HID * HID * 2);
    unsigned short* Wt_o2  = (unsigned short*)alloc((size_t)HID * DD * 2);
    // Region R: CSR scratch {cew, cnt, bsum, boff} then reused as {ss, sd} in layers.
    size_t cew_b = (size_t)NT * EE * 4;           // 3.84 MB
    size_t cnt_b = (size_t)NT * NN * 4;           // 0.48 MB
    char* R = alloc(cew_b + cnt_b + 2 * 2048 * 4);
    float* cew = (float*)R;
    int* cnt   = (int*)(R + cew_b);
    int* bsum  = (int*)(R + cew_b + cnt_b);
    int* boff  = bsum + 2048;
    float* ss  = (float*)R;                       // alias: live only after ewg_kernel
    float* sd  = ss + (size_t)NT * NN * NH;
    int* roff  = (int*)alloc(((size_t)NT * NN + 1) * 4);
    int* rsrc  = (int*)alloc((size_t)NT * EE * 4);
    float* ewg = (float*)alloc((size_t)NN * 4);
    float* cpart = (float*)alloc((size_t)256 * DD * 4);

    const int NSC = (NT * NN + 255) / 256;  // 469 scan blocks

    // ---- weight conversions (bf16, transposed to [N][K]) ----
    wconv_k<<<(DD * HID + 255) / 256, 256, 0, stream>>>(in_W, Wt_in, 1, DD, HID);
    wconv_k<<<(LL * NT * HID * HID + 255) / 256, 256, 0, stream>>>(gat_W, Wt_gat, LL * NT, HID, HID);
    wconv_k<<<(HID * HID + 255) / 256, 256, 0, stream>>>(out_W1, Wt_o1, 1, HID, HID);
    wconv_k<<<(HID * DD + 255) / 256, 256, 0, stream>>>(out_W2, Wt_o2, 1, HID, DD);
    xconv_k<<<(NN * DD / 4 + 255) / 256, 256, 0, stream>>>(x, xb);

    // ---- input projection + LN + GELU -> h0 (fp32 in d_out h-slot, bf16 in hb) ----
    gemm_mfma_k<<<dim3(HID / 128, (NN + 127) / 128), 256, 0, stream>>>(
        xb, Wt_in, in_b, Cf32, nullptr, NN, DD, HID);
    ln_gelu_k<<<NN / 4, 256, 0, stream>>>(Cf32, in_g, in_bb, out_h[0], hb);

    // ---- CSR build (batched, all 3 types) ----
    hipMemsetAsync(cnt, 0, cnt_b, stream);
    hist_k<<<(NT * EE + 255) / 256, 256, 0, stream>>>(ei, cnt);
    scan1_k<<<NSC, 256, 0, stream>>>(cnt, bsum, NT * NN);
    scan2_k<<<1, 512, 0, stream>>>(bsum, boff, NSC);
    scan3_k<<<NSC, 256, 0, stream>>>(cnt, boff, roff, NT * NN);
    hipMemsetAsync(cnt, 0, cnt_b, stream);
    scatter_k<<<(NT * EE + 255) / 256, 256, 0, stream>>>(ei, ew, roff, cnt, rsrc, cew);
    ewg_kernel<<<(NN + 255) / 256, 256, 0, stream>>>(roff, cew, ewg);

    // ---- message-passing layers ----
    const float* hin_f = out_h[0];
    for (int i = 0; i < LL; i++) {
        // one batched GEMM: xpa[NN][768] = hb @ [Wt for 3 types]
        gemm_mfma_k<<<dim3(NP / 128, (NN + 127) / 128), 256, 0, stream>>>(
            hb, Wt_gat + (size_t)i * NP * HID, nullptr, nullptr, xpa, NN, HID, NP);
        compute_s_k<<<NT * (NN / 4), 256, 0, stream>>>(
            xpa, gat_as + (size_t)i * NT * HID, gat_ad + (size_t)i * NT * HID, ss, sd);
        layer_k<<<NN / 4, 256, 0, stream>>>(
            xpa, ss, sd, roff, rsrc, gat_b + (size_t)i * NT * HID,
            hin_f, liq, gate_W, gate_b, ewg, ln_g + i * HID, ln_b + i * HID,
            out_h[i], hb);   // hb overwritten in place (this layer's GEMM already done)
        hin_f = out_h[i];
    }

    // ---- output head ----
    gemm_mfma_k<<<dim3(HID / 128, (NN + 127) / 128), 256, 0, stream>>>(
        hb, Wt_o1, out_b1, Cf32, nullptr, NN, HID, HID);
    ln_gelu_k<<<NN / 4, 256, 0, stream>>>(Cf32, out_g, out_bb, nullptr, hb);
    gemm_mfma_k<<<dim3(DD / 128, (NN + 127) / 128), 256, 0, stream>>>(
        hb, Wt_o2, out_b2, out_ho, nullptr, NN, HID, DD);

    // ---- readout ----
    colpart_k<<<256, 128, 0, stream>>>(out_ho, cpart);
    readout_k<<<1, 256, 0, stream>>>(cpart, ro_W1, ro_b1, ro_W2, ro_b2, out_surf);
}

// Round 5
// 838.593 us; speedup vs baseline: 3.3475x; 1.0150x over previous
//
#include <hip/hip_runtime.h>
#include <hip/hip_bf16.h>
#include <math.h>

#define NN 40000
#define EE 320000
#define NT 3
#define LL 3
#define DD 128
#define HID 256
#define NH 4
#define CC 64
#define NP 768   // NT*HID: batched projection width
#define LGRID 2048  // layer_k persistent blocks (8192 waves)

typedef __attribute__((ext_vector_type(8))) short short8;
typedef __attribute__((ext_vector_type(4))) float f32x4;

__device__ __forceinline__ float gelu_f(float x) {
    return 0.5f * x * (1.0f + erff(x * 0.70710678118654752440f));
}
__device__ __forceinline__ float lrelu_f(float x) {
    return x > 0.0f ? x : 0.2f * x;
}
__device__ __forceinline__ float bf2f(unsigned short u) {
    unsigned int x = ((unsigned int)u) << 16;
    float f;
    __builtin_memcpy(&f, &x, 4);
    return f;
}
__device__ __forceinline__ unsigned short f2bf(float f) {
    __hip_bfloat16 h = __float2bfloat16(f);
    unsigned short u;
    __builtin_memcpy(&u, &h, 2);
    return u;
}
__device__ __forceinline__ void gload16(const void* g, void* l) {
    __builtin_amdgcn_global_load_lds(
        (const __attribute__((address_space(1))) unsigned int*)g,
        (__attribute__((address_space(3))) unsigned int*)l, 16, 0, 0);
}

// ---------------- weight transpose + bf16 convert: W[m][K][N] -> Wt[m][N][K] ----------------
__global__ void wconv_k(const float* __restrict__ W, unsigned short* __restrict__ Wt,
                        int nmat, int K, int N) {
    int idx = blockIdx.x * 256 + threadIdx.x;
    int tot = nmat * K * N;
    if (idx >= tot) return;
    int m = idx / (K * N);
    int rem = idx - m * (K * N);
    int k = rem / N;
    int n = rem - k * N;
    Wt[(size_t)m * K * N + (size_t)n * K + k] = f2bf(W[idx]);
}

// ---------------- x fp32 -> bf16 ----------------
__global__ void xconv_k(const float* __restrict__ x, unsigned short* __restrict__ xb) {
    int idx = blockIdx.x * 256 + threadIdx.x;
    if (idx >= NN * DD / 4) return;
    float4 v = *reinterpret_cast<const float4*>(&x[(size_t)idx * 4]);
    ushort4 o;
    o.x = f2bf(v.x); o.y = f2bf(v.y); o.z = f2bf(v.z); o.w = f2bf(v.w);
    *reinterpret_cast<ushort4*>(&xb[(size_t)idx * 4]) = o;
}

// ---------------- MFMA bf16 GEMM: C[M][N] = A[M][K] @ Bt[N][K]^T (+bias) ----------------
__global__ __launch_bounds__(256) void gemm_mfma_k(const unsigned short* __restrict__ A,
                                                   const unsigned short* __restrict__ Bt,
                                                   const float* __restrict__ bias,
                                                   float* __restrict__ Cf,
                                                   unsigned short* __restrict__ Cb,
                                                   int M, int K, int N) {
    __shared__ __align__(16) short As[128 * 32];
    __shared__ __align__(16) short Bs[128 * 32];
    int bm = blockIdx.y * 128, bn = blockIdx.x * 128;
    int tid = threadIdx.x;
    int lane = tid & 63, w = tid >> 6;
    int wr = w >> 1, wc = w & 1;
    int l16 = lane & 15, kgrp = lane >> 4;
    f32x4 acc[4][4] = {};
    for (int k0 = 0; k0 < K; k0 += 32) {
        #pragma unroll
        for (int i = 0; i < 2; i++) {
            int chunk = (i * 4 + w) * 64 + lane;     // 0..511
            int row = chunk >> 2, kq = chunk & 3;
            int grow = bm + row; if (grow > M - 1) grow = M - 1;
            gload16(A + (size_t)grow * K + k0 + kq * 8, &As[(i * 4 + w) * 512]);
        }
        #pragma unroll
        for (int i = 0; i < 2; i++) {
            int chunk = (i * 4 + w) * 64 + lane;
            int row = chunk >> 2, kq = chunk & 3;
            gload16(Bt + (size_t)(bn + row) * K + k0 + kq * 8, &Bs[(i * 4 + w) * 512]);
        }
        __syncthreads();
        short8 af[4], bf[4];
        #pragma unroll
        for (int mi = 0; mi < 4; mi++) {
            int row = wr * 64 + mi * 16 + l16;
            af[mi] = *reinterpret_cast<const short8*>(&As[row * 32 + kgrp * 8]);
        }
        #pragma unroll
        for (int ni = 0; ni < 4; ni++) {
            int nrow = wc * 64 + ni * 16 + l16;
            bf[ni] = *reinterpret_cast<const short8*>(&Bs[nrow * 32 + kgrp * 8]);
        }
        #pragma unroll
        for (int mi = 0; mi < 4; mi++)
            #pragma unroll
            for (int ni = 0; ni < 4; ni++)
                acc[mi][ni] = __builtin_amdgcn_mfma_f32_16x16x32_bf16(af[mi], bf[ni], acc[mi][ni], 0, 0, 0);
        __syncthreads();
    }
    #pragma unroll
    for (int mi = 0; mi < 4; mi++) {
        #pragma unroll
        for (int r = 0; r < 4; r++) {
            int row = bm + wr * 64 + mi * 16 + (lane >> 4) * 4 + r;
            if (row < M) {
                #pragma unroll
                for (int ni = 0; ni < 4; ni++) {
                    int col = bn + wc * 64 + ni * 16 + l16;
                    float v = acc[mi][ni][r] + (bias ? bias[col] : 0.0f);
                    if (Cf) Cf[(size_t)row * N + col] = v;
                    if (Cb) Cb[(size_t)row * N + col] = f2bf(v);
                }
            }
        }
    }
}

// ---------------- LayerNorm + GELU, one wave per row of 256 ----------------
__global__ __launch_bounds__(256) void ln_gelu_k(const float* __restrict__ y,
                                                 const float* __restrict__ g,
                                                 const float* __restrict__ b,
                                                 float* __restrict__ outf,
                                                 unsigned short* __restrict__ outb) {
    int n = blockIdx.x * 4 + (threadIdx.x >> 6);
    int lane = threadIdx.x & 63;
    float4 v = *reinterpret_cast<const float4*>(&y[(size_t)n * HID + lane * 4]);
    float s = v.x + v.y + v.z + v.w;
    float q = v.x * v.x + v.y * v.y + v.z * v.z + v.w * v.w;
    #pragma unroll
    for (int o = 32; o; o >>= 1) { s += __shfl_xor(s, o); q += __shfl_xor(q, o); }
    float mean = s * (1.0f / HID);
    float var = q * (1.0f / HID) - mean * mean;
    float rs = rsqrtf(var + 1e-5f);
    float4 gv = *reinterpret_cast<const float4*>(&g[lane * 4]);
    float4 bv = *reinterpret_cast<const float4*>(&b[lane * 4]);
    float o0 = gelu_f(gv.x * (v.x - mean) * rs + bv.x);
    float o1 = gelu_f(gv.y * (v.y - mean) * rs + bv.y);
    float o2 = gelu_f(gv.z * (v.z - mean) * rs + bv.z);
    float o3 = gelu_f(gv.w * (v.w - mean) * rs + bv.w);
    if (outf) {
        float4 ov = {o0, o1, o2, o3};
        *reinterpret_cast<float4*>(&outf[(size_t)n * HID + lane * 4]) = ov;
    }
    ushort4 ob;
    ob.x = f2bf(o0); ob.y = f2bf(o1); ob.z = f2bf(o2); ob.w = f2bf(o3);
    *reinterpret_cast<ushort4*>(&outb[(size_t)n * HID + lane * 4]) = ob;
}

// ---------------- CSR build: batched over 3 edge types ----------------
__global__ void hist_k(const int* __restrict__ ei, int* __restrict__ cnt) {
    int gid = blockIdx.x * 256 + threadIdx.x;
    if (gid >= NT * EE) return;
    int t = gid / EE, e = gid - t * EE;
    int dst = ei[(size_t)t * 2 * EE + EE + e];
    atomicAdd(&cnt[t * NN + dst], 1);
}

__global__ __launch_bounds__(256) void scan1_k(const int* __restrict__ cnt, int* __restrict__ bsum, int n) {
    int i = blockIdx.x * 256 + threadIdx.x;
    int v = (i < n) ? cnt[i] : 0;
    #pragma unroll
    for (int o = 32; o; o >>= 1) v += __shfl_xor(v, o);
    __shared__ int s4[4];
    if ((threadIdx.x & 63) == 0) s4[threadIdx.x >> 6] = v;
    __syncthreads();
    if (threadIdx.x == 0) bsum[blockIdx.x] = s4[0] + s4[1] + s4[2] + s4[3];
}

__global__ __launch_bounds__(512) void scan2_k(const int* __restrict__ bsum, int* __restrict__ boff, int nb) {
    __shared__ int sh[512];
    int t = threadIdx.x;
    int v = (t < nb) ? bsum[t] : 0;
    sh[t] = v;
    __syncthreads();
    for (int o = 1; o < 512; o <<= 1) {
        int tv = (t >= o) ? sh[t - o] : 0;
        __syncthreads();
        sh[t] += tv;
        __syncthreads();
    }
    if (t < nb) boff[t] = sh[t] - v;
}

__global__ __launch_bounds__(256) void scan3_k(const int* __restrict__ cnt, const int* __restrict__ boff,
                                               int* __restrict__ roff, int n) {
    int i = blockIdx.x * 256 + threadIdx.x;
    int lane = threadIdx.x & 63, w = threadIdx.x >> 6;
    int v = (i < n) ? cnt[i] : 0;
    int s = v;
    #pragma unroll
    for (int o = 1; o < 64; o <<= 1) {
        int tv = __shfl_up(s, o);
        if (lane >= o) s += tv;
    }
    __shared__ int ws_[4];
    if (lane == 63) ws_[w] = s;
    __syncthreads();
    int add = 0;
    for (int k = 0; k < 4; k++) if (k < w) add += ws_[k];
    int incl = s + add + boff[blockIdx.x];
    if (i < n) roff[i] = incl - v;
    if (i == n - 1) roff[n] = incl;
}

__global__ void scatter_k(const int* __restrict__ ei, const float* __restrict__ ew,
                          const int* __restrict__ roff, int* __restrict__ cur,
                          int* __restrict__ csr_src, float* __restrict__ csr_ew) {
    int gid = blockIdx.x * 256 + threadIdx.x;
    if (gid >= NT * EE) return;
    int t = gid / EE, e = gid - t * EE;
    int src = ei[(size_t)t * 2 * EE + e];
    int dst = ei[(size_t)t * 2 * EE + EE + e];
    int pos = roff[t * NN + dst] + atomicAdd(&cur[t * NN + dst], 1);
    csr_src[pos] = src;
    csr_ew[pos] = ew[gid];
}

// ---------------- edge-weight gate from CSR ----------------
__global__ void ewg_kernel(const int* __restrict__ roff, const float* __restrict__ csr_ew,
                           float* __restrict__ ewg) {
    int n = blockIdx.x * 256 + threadIdx.x;
    if (n >= NN) return;
    float ws = 0.0f;
    int dg = 0;
    for (int t = 0; t < NT; t++) {
        int beg = roff[t * NN + n], end = roff[t * NN + n + 1];
        dg += end - beg;
        for (int e = beg; e < end; e++) ws += csr_ew[e];
    }
    float m = dg > 1 ? (float)dg : 1.0f;
    float z = ws / m;
    ewg[n] = 0.5f + 1.0f / (1.0f + __expf(-z));
}

// ---------------- per-(node,head) attention score inputs (bf16 xpa [NN][768]) -----
__global__ __launch_bounds__(256) void compute_s_k(const unsigned short* __restrict__ xpa,
                                                   const float* __restrict__ asrc,  // [3][256]
                                                   const float* __restrict__ adst,
                                                   float* __restrict__ ss,          // [3][NN][4]
                                                   float* __restrict__ sd) {
    int t = blockIdx.x / (NN / 4);
    int node = (blockIdx.x % (NN / 4)) * 4 + (threadIdx.x >> 6);
    int lane = threadIdx.x & 63;
    ushort4 v = *reinterpret_cast<const ushort4*>(&xpa[(size_t)node * NP + t * HID + lane * 4]);
    float4 av = *reinterpret_cast<const float4*>(&asrc[t * HID + lane * 4]);
    float4 dv = *reinterpret_cast<const float4*>(&adst[t * HID + lane * 4]);
    float x0 = bf2f(v.x), x1 = bf2f(v.y), x2 = bf2f(v.z), x3 = bf2f(v.w);
    float p = x0 * av.x + x1 * av.y + x2 * av.z + x3 * av.w;
    float q = x0 * dv.x + x1 * dv.y + x2 * dv.z + x3 * dv.w;
    #pragma unroll
    for (int o = 8; o; o >>= 1) { p += __shfl_xor(p, o); q += __shfl_xor(q, o); }
    if ((lane & 15) == 0) {
        ss[((size_t)t * NN + node) * NH + (lane >> 4)] = p;
        sd[((size_t)t * NN + node) * NH + (lane >> 4)] = q;
    }
}

// ---- fused layer: 3-type GAT agg (no-max softmax: scores bounded ~|0.5|) + gate + ewg
//      + residual + LN + GELU. Persistent grid-stride waves; hin read from bf16 hb.
__global__ __launch_bounds__(256) void layer_k(const unsigned short* __restrict__ xpa, // [NN][768]
                                               const float* __restrict__ ss,
                                               const float* __restrict__ sd,
                                               const int* __restrict__ roff,
                                               const int* __restrict__ rsrc,
                                               const float* __restrict__ gatb,  // [3][256]
                                               const float* __restrict__ liq,
                                               const float* __restrict__ gW,    // [260]
                                               const float* __restrict__ gb,    // [1]
                                               const float* __restrict__ ewg,
                                               const float* __restrict__ lg,
                                               const float* __restrict__ lb,
                                               float* __restrict__ hout,
                                               unsigned short* __restrict__ hb) { // in+out (in-place rows)
    int wid = blockIdx.x * 4 + (threadIdx.x >> 6);
    int lane = threadIdx.x & 63;
    int h = lane >> 4;
    const int nw = LGRID * 4;
    // node-invariant loads
    float4 bb0 = *reinterpret_cast<const float4*>(&gatb[lane * 4]);
    float4 bb1 = *reinterpret_cast<const float4*>(&gatb[HID + lane * 4]);
    float4 bb2 = *reinterpret_cast<const float4*>(&gatb[2 * HID + lane * 4]);
    float bs0 = bb0.x + bb1.x + bb2.x;
    float bs1 = bb0.y + bb1.y + bb2.y;
    float bs2 = bb0.z + bb1.z + bb2.z;
    float bs3 = bb0.w + bb1.w + bb2.w;
    float4 gwv = *reinterpret_cast<const float4*>(&gW[lane * 4]);
    float gwl = (lane < 4) ? gW[HID + lane] : 0.0f;
    float gb0 = gb[0];
    float4 lgv = *reinterpret_cast<const float4*>(&lg[lane * 4]);
    float4 lbv = *reinterpret_cast<const float4*>(&lb[lane * 4]);

    for (int node = wid; node < NN; node += nw) {
        float agg0 = 0, agg1 = 0, agg2 = 0, agg3 = 0;
        #pragma unroll
        for (int t = 0; t < NT; t++) {
            int base = t * NN;
            int beg = roff[base + node], end = roff[base + node + 1];
            if (beg == end) continue;
            float sdh = sd[(size_t)(base + node) * NH + h];
            float den = 0, a0 = 0, a1 = 0, a2 = 0, a3 = 0;
            int sp = rsrc[beg];
            float svp = ss[(size_t)(base + sp) * NH + h];
            ushort4 xrp = *reinterpret_cast<const ushort4*>(&xpa[(size_t)sp * NP + t * HID + lane * 4]);
            for (int e = beg; e < end; e++) {
                float sv_c = svp;
                ushort4 xr_c = xrp;
                int en = (e + 1 < end) ? (e + 1) : e;   // branchless clamp
                int sn = rsrc[en];
                svp = ss[(size_t)(base + sn) * NH + h];
                xrp = *reinterpret_cast<const ushort4*>(&xpa[(size_t)sn * NP + t * HID + lane * 4]);
                float wg = __expf(lrelu_f(sv_c + sdh));  // no max-shift: |score| < ~1
                den += wg;
                a0 += wg * bf2f(xr_c.x);
                a1 += wg * bf2f(xr_c.y);
                a2 += wg * bf2f(xr_c.z);
                a3 += wg * bf2f(xr_c.w);
            }
            float inv = 1.0f / (den + 1e-16f);
            agg0 += a0 * inv; agg1 += a1 * inv; agg2 += a2 * inv; agg3 += a3 * inv;
        }
        agg0 += bs0; agg1 += bs1; agg2 += bs2; agg3 += bs3;
        // gate logit (wave reduce)
        float part = agg0 * gwv.x + agg1 * gwv.y + agg2 * gwv.z + agg3 * gwv.w;
        if (lane < 4) part += liq[node * 4 + lane] * gwl;
        #pragma unroll
        for (int o = 32; o; o >>= 1) part += __shfl_xor(part, o);
        float gate = 1.0f / (1.0f + __expf(-(part + gb0)));
        float eg = ewg[node];
        ushort4 hu = *reinterpret_cast<const ushort4*>(&hb[(size_t)node * HID + lane * 4]);
        float h0 = bf2f(hu.x), h1 = bf2f(hu.y), h2 = bf2f(hu.z), h3 = bf2f(hu.w);
        float v0 = (gate * agg0 + (1.0f - gate) * h0) * eg + h0;
        float v1 = (gate * agg1 + (1.0f - gate) * h1) * eg + h1;
        float v2 = (gate * agg2 + (1.0f - gate) * h2) * eg + h2;
        float v3 = (gate * agg3 + (1.0f - gate) * h3) * eg + h3;
        float s = v0 + v1 + v2 + v3;
        float q = v0 * v0 + v1 * v1 + v2 * v2 + v3 * v3;
        #pragma unroll
        for (int o = 32; o; o >>= 1) { s += __shfl_xor(s, o); q += __shfl_xor(q, o); }
        float mean = s * (1.0f / HID);
        float var = q * (1.0f / HID) - mean * mean;
        float rs = rsqrtf(var + 1e-5f);
        float o0 = gelu_f(lgv.x * (v0 - mean) * rs + lbv.x);
        float o1 = gelu_f(lgv.y * (v1 - mean) * rs + lbv.y);
        float o2 = gelu_f(lgv.z * (v2 - mean) * rs + lbv.z);
        float o3 = gelu_f(lgv.w * (v3 - mean) * rs + lbv.w);
        float4 ov = {o0, o1, o2, o3};
        *reinterpret_cast<float4*>(&hout[(size_t)node * HID + lane * 4]) = ov;
        ushort4 ob;
        ob.x = f2bf(o0); ob.y = f2bf(o1); ob.z = f2bf(o2); ob.w = f2bf(o3);
        *reinterpret_cast<ushort4*>(&hb[(size_t)node * HID + lane * 4]) = ob;
    }
}

// ---------------- column partial sums of ho (N x D) ----------------
__global__ __launch_bounds__(128) void colpart_k(const float* __restrict__ ho,
                                                 float* __restrict__ part) {
    int c = threadIdx.x, b = blockIdx.x;
    float s = 0.0f;
    for (int r = b; r < NN; r += 256) s += ho[(size_t)r * DD + c];
    part[b * DD + c] = s;
}

// ---------------- readout MLP (single block) ----------------
__global__ __launch_bounds__(256) void readout_k(const float* __restrict__ part,
                                                 const float* __restrict__ W1,
                                                 const float* __restrict__ b1,
                                                 const float* __restrict__ W2,
                                                 const float* __restrict__ b2,
                                                 float* __restrict__ surf) {
    __shared__ float m[DD];
    __shared__ float a1[HID];
    int t = threadIdx.x;
    if (t < DD) {
        float s = 0.0f;
        for (int b = 0; b < 256; b++) s += part[b * DD + t];
        m[t] = s / (float)NN;
    }
    __syncthreads();
    float s1 = b1[t];
    for (int k = 0; k < DD; k++) s1 += m[k] * W1[k * HID + t];
    a1[t] = gelu_f(s1);
    __syncthreads();
    float s2 = b2[t];
    for (int k = 0; k < HID; k++) s2 += a1[k] * W2[k * HID + t];
    surf[t] = s2;
}

extern "C" void kernel_launch(void* const* d_in, const int* in_sizes, int n_in,
                              void* d_out, int out_size, void* d_ws, size_t ws_size,
                              hipStream_t stream) {
    const float* x       = (const float*)d_in[0];
    const float* liq     = (const float*)d_in[1];
    const int*   ei      = (const int*)d_in[2];
    const float* ew      = (const float*)d_in[3];
    const float* in_W    = (const float*)d_in[4];
    const float* in_b    = (const float*)d_in[5];
    const float* in_g    = (const float*)d_in[6];
    const float* in_bb   = (const float*)d_in[7];
    const float* gat_W   = (const float*)d_in[8];
    const float* gat_as  = (const float*)d_in[9];
    const float* gat_ad  = (const float*)d_in[10];
    const float* gat_b   = (const float*)d_in[11];
    const float* ln_g    = (const float*)d_in[12];
    const float* ln_b    = (const float*)d_in[13];
    const float* gate_W  = (const float*)d_in[14];
    const float* gate_b  = (const float*)d_in[15];
    const float* out_W1  = (const float*)d_in[16];
    const float* out_b1  = (const float*)d_in[17];
    const float* out_g   = (const float*)d_in[18];
    const float* out_bb  = (const float*)d_in[19];
    const float* out_W2  = (const float*)d_in[20];
    const float* out_b2  = (const float*)d_in[21];
    const float* ro_W1   = (const float*)d_in[22];
    const float* ro_b1   = (const float*)d_in[23];
    const float* ro_W2   = (const float*)d_in[24];
    const float* ro_b2   = (const float*)d_in[25];

    float* out = (float*)d_out;
    float* out_ho   = out;
    float* out_surf = out + (size_t)NN * DD;
    float* out_h[3];
    out_h[0] = out_surf + HID;
    out_h[1] = out_h[0] + (size_t)NN * HID;
    out_h[2] = out_h[1] + (size_t)NN * HID;

    char* wsb = (char*)d_ws;
    size_t off = 0;
    auto alloc = [&](size_t bytes) { char* p = wsb + off; off += (bytes + 255) & ~(size_t)255; return p; };
    unsigned short* xpa = (unsigned short*)alloc((size_t)NN * NP * 2);
    float* Cf32 = (float*)xpa;               // alias: front of xpa (dead before layer GEMM)
    unsigned short* xb = xpa + (size_t)NN * 512;  // alias: after Cf32
    unsigned short* hb = (unsigned short*)alloc((size_t)NN * HID * 2);  // bf16 h shadow
    unsigned short* Wt_in  = (unsigned short*)alloc((size_t)DD * HID * 2);
    unsigned short* Wt_gat = (unsigned short*)alloc((size_t)LL * NT * HID * HID * 2); // [L][768][256]
    unsigned short* Wt_o1  = (unsigned short*)alloc((size_t)HID * HID * 2);
    unsigned short* Wt_o2  = (unsigned short*)alloc((size_t)HID * DD * 2);
    size_t cew_b = (size_t)NT * EE * 4;
    size_t cnt_b = (size_t)NT * NN * 4;
    char* R = alloc(cew_b + cnt_b + 2 * 2048 * 4);
    float* cew = (float*)R;
    int* cnt   = (int*)(R + cew_b);
    int* bsum  = (int*)(R + cew_b + cnt_b);
    int* boff  = bsum + 2048;
    float* ss  = (float*)R;                  // alias: live only after ewg_kernel
    float* sd  = ss + (size_t)NT * NN * NH;
    int* roff  = (int*)alloc(((size_t)NT * NN + 1) * 4);
    int* rsrc  = (int*)alloc((size_t)NT * EE * 4);
    float* ewg = (float*)alloc((size_t)NN * 4);
    float* cpart = (float*)alloc((size_t)256 * DD * 4);

    const int NSC = (NT * NN + 255) / 256;

    // ---- weight conversions ----
    wconv_k<<<(DD * HID + 255) / 256, 256, 0, stream>>>(in_W, Wt_in, 1, DD, HID);
    wconv_k<<<(LL * NT * HID * HID + 255) / 256, 256, 0, stream>>>(gat_W, Wt_gat, LL * NT, HID, HID);
    wconv_k<<<(HID * HID + 255) / 256, 256, 0, stream>>>(out_W1, Wt_o1, 1, HID, HID);
    wconv_k<<<(HID * DD + 255) / 256, 256, 0, stream>>>(out_W2, Wt_o2, 1, HID, DD);
    xconv_k<<<(NN * DD / 4 + 255) / 256, 256, 0, stream>>>(x, xb);

    // ---- input projection + LN + GELU -> h0 (bf16 in hb only) ----
    gemm_mfma_k<<<dim3(HID / 128, (NN + 127) / 128), 256, 0, stream>>>(
        xb, Wt_in, in_b, Cf32, nullptr, NN, DD, HID);
    ln_gelu_k<<<NN / 4, 256, 0, stream>>>(Cf32, in_g, in_bb, nullptr, hb);

    // ---- CSR build ----
    hipMemsetAsync(cnt, 0, cnt_b, stream);
    hist_k<<<(NT * EE + 255) / 256, 256, 0, stream>>>(ei, cnt);
    scan1_k<<<NSC, 256, 0, stream>>>(cnt, bsum, NT * NN);
    scan2_k<<<1, 512, 0, stream>>>(bsum, boff, NSC);
    scan3_k<<<NSC, 256, 0, stream>>>(cnt, boff, roff, NT * NN);
    hipMemsetAsync(cnt, 0, cnt_b, stream);
    scatter_k<<<(NT * EE + 255) / 256, 256, 0, stream>>>(ei, ew, roff, cnt, rsrc, cew);
    ewg_kernel<<<(NN + 255) / 256, 256, 0, stream>>>(roff, cew, ewg);

    // ---- message-passing layers ----
    for (int i = 0; i < LL; i++) {
        gemm_mfma_k<<<dim3(NP / 128, (NN + 127) / 128), 256, 0, stream>>>(
            hb, Wt_gat + (size_t)i * NP * HID, nullptr, nullptr, xpa, NN, HID, NP);
        compute_s_k<<<NT * (NN / 4), 256, 0, stream>>>(
            xpa, gat_as + (size_t)i * NT * HID, gat_ad + (size_t)i * NT * HID, ss, sd);
        layer_k<<<LGRID, 256, 0, stream>>>(
            xpa, ss, sd, roff, rsrc, gat_b + (size_t)i * NT * HID,
            liq, gate_W, gate_b, ewg, ln_g + i * HID, ln_b + i * HID,
            out_h[i], hb);
    }

    // ---- output head ----
    gemm_mfma_k<<<dim3(HID / 128, (NN + 127) / 128), 256, 0, stream>>>(
        hb, Wt_o1, out_b1, Cf32, nullptr, NN, HID, HID);
    ln_gelu_k<<<NN / 4, 256, 0, stream>>>(Cf32, out_g, out_bb, nullptr, hb);
    gemm_mfma_k<<<dim3(DD / 128, (NN + 127) / 128), 256, 0, stream>>>(
        hb, Wt_o2, out_b2, out_ho, nullptr, NN, HID, DD);

    // ---- readout ----
    colpart_k<<<256, 128, 0, stream>>>(out_ho, cpart);
    readout_k<<<1, 256, 0, stream>>>(cpart, ro_W1, ro_b1, ro_W2, ro_b2, out_surf);
}

// Round 6
// 825.189 us; speedup vs baseline: 3.4018x; 1.0162x over previous
//
#include <hip/hip_runtime.h>
#include <hip/hip_bf16.h>
#include <hip/hip_fp8.h>
#include <math.h>

#define NN 40000
#define EE 320000
#define NT 3
#define LL 3
#define DD 128
#define HID 256
#define NH 4
#define CC 64
#define NP 768   // NT*HID: batched projection width
#define LGRID 2048  // layer_k persistent blocks (8192 waves)

typedef __attribute__((ext_vector_type(8))) short short8;
typedef __attribute__((ext_vector_type(4))) float f32x4;

__device__ __forceinline__ float gelu_f(float x) {
    return 0.5f * x * (1.0f + erff(x * 0.70710678118654752440f));
}
__device__ __forceinline__ float lrelu_f(float x) {
    return x > 0.0f ? x : 0.2f * x;
}
__device__ __forceinline__ float bf2f(unsigned short u) {
    unsigned int x = ((unsigned int)u) << 16;
    float f;
    __builtin_memcpy(&f, &x, 4);
    return f;
}
__device__ __forceinline__ unsigned short f2bf(float f) {
    __hip_bfloat16 h = __float2bfloat16(f);
    unsigned short u;
    __builtin_memcpy(&u, &h, 2);
    return u;
}
__device__ __forceinline__ float fp8tof(unsigned char b) {
    __hip_fp8_e4m3 q;
    q.__x = (__hip_fp8_storage_t)b;
    return (float)q;
}
__device__ __forceinline__ unsigned char ftofp8(float f) {
    __hip_fp8_e4m3 q(f);
    return (unsigned char)q.__x;
}
__device__ __forceinline__ void gload16(const void* g, void* l) {
    __builtin_amdgcn_global_load_lds(
        (const __attribute__((address_space(1))) unsigned int*)g,
        (__attribute__((address_space(3))) unsigned int*)l, 16, 0, 0);
}

// ---------------- weight transpose + bf16 convert: W[m][K][N] -> Wt[m][N][K] ----------------
__global__ void wconv_k(const float* __restrict__ W, unsigned short* __restrict__ Wt,
                        int nmat, int K, int N) {
    int idx = blockIdx.x * 256 + threadIdx.x;
    int tot = nmat * K * N;
    if (idx >= tot) return;
    int m = idx / (K * N);
    int rem = idx - m * (K * N);
    int k = rem / N;
    int n = rem - k * N;
    Wt[(size_t)m * K * N + (size_t)n * K + k] = f2bf(W[idx]);
}

// ---------------- x fp32 -> bf16 ----------------
__global__ void xconv_k(const float* __restrict__ x, unsigned short* __restrict__ xb) {
    int idx = blockIdx.x * 256 + threadIdx.x;
    if (idx >= NN * DD / 4) return;
    float4 v = *reinterpret_cast<const float4*>(&x[(size_t)idx * 4]);
    ushort4 o;
    o.x = f2bf(v.x); o.y = f2bf(v.y); o.z = f2bf(v.z); o.w = f2bf(v.w);
    *reinterpret_cast<ushort4*>(&xb[(size_t)idx * 4]) = o;
}

// ---------------- MFMA bf16 GEMM: C[M][N] = A[M][K] @ Bt[N][K]^T (+bias) ----------------
// Outputs: Cf (fp32), Cb (bf16), Cq (fp8 e4m3) — any subset. XCD-chunked block swizzle.
__global__ __launch_bounds__(256) void gemm_mfma_k(const unsigned short* __restrict__ A,
                                                   const unsigned short* __restrict__ Bt,
                                                   const float* __restrict__ bias,
                                                   float* __restrict__ Cf,
                                                   unsigned short* __restrict__ Cb,
                                                   unsigned char* __restrict__ Cq,
                                                   int M, int K, int N) {
    __shared__ __align__(16) short As[128 * 32];
    __shared__ __align__(16) short Bs[128 * 32];
    // bijective XCD swizzle: XCD k gets a contiguous chunk of flat block space,
    // x (N-tile) fastest so each XCD reuses its A panels across all N-tiles.
    int gdx = gridDim.x;
    int nwg = gdx * gridDim.y;
    int f = blockIdx.y * gdx + blockIdx.x;
    int q8 = nwg >> 3, r8 = nwg & 7;
    int xcd = f & 7, idx8 = f >> 3;
    int nf = (xcd < r8 ? xcd * (q8 + 1) : r8 * (q8 + 1) + (xcd - r8) * q8) + idx8;
    int bn = (nf % gdx) * 128;
    int bm = (nf / gdx) * 128;
    int tid = threadIdx.x;
    int lane = tid & 63, w = tid >> 6;
    int wr = w >> 1, wc = w & 1;
    int l16 = lane & 15, kgrp = lane >> 4;
    f32x4 acc[4][4] = {};
    for (int k0 = 0; k0 < K; k0 += 32) {
        #pragma unroll
        for (int i = 0; i < 2; i++) {
            int chunk = (i * 4 + w) * 64 + lane;     // 0..511
            int row = chunk >> 2, kq = chunk & 3;
            int grow = bm + row; if (grow > M - 1) grow = M - 1;
            gload16(A + (size_t)grow * K + k0 + kq * 8, &As[(i * 4 + w) * 512]);
        }
        #pragma unroll
        for (int i = 0; i < 2; i++) {
            int chunk = (i * 4 + w) * 64 + lane;
            int row = chunk >> 2, kq = chunk & 3;
            gload16(Bt + (size_t)(bn + row) * K + k0 + kq * 8, &Bs[(i * 4 + w) * 512]);
        }
        __syncthreads();
        short8 af[4], bf[4];
        #pragma unroll
        for (int mi = 0; mi < 4; mi++) {
            int row = wr * 64 + mi * 16 + l16;
            af[mi] = *reinterpret_cast<const short8*>(&As[row * 32 + kgrp * 8]);
        }
        #pragma unroll
        for (int ni = 0; ni < 4; ni++) {
            int nrow = wc * 64 + ni * 16 + l16;
            bf[ni] = *reinterpret_cast<const short8*>(&Bs[nrow * 32 + kgrp * 8]);
        }
        #pragma unroll
        for (int mi = 0; mi < 4; mi++)
            #pragma unroll
            for (int ni = 0; ni < 4; ni++)
                acc[mi][ni] = __builtin_amdgcn_mfma_f32_16x16x32_bf16(af[mi], bf[ni], acc[mi][ni], 0, 0, 0);
        __syncthreads();
    }
    #pragma unroll
    for (int mi = 0; mi < 4; mi++) {
        #pragma unroll
        for (int r = 0; r < 4; r++) {
            int row = bm + wr * 64 + mi * 16 + (lane >> 4) * 4 + r;
            if (row < M) {
                #pragma unroll
                for (int ni = 0; ni < 4; ni++) {
                    int col = bn + wc * 64 + ni * 16 + l16;
                    float v = acc[mi][ni][r] + (bias ? bias[col] : 0.0f);
                    if (Cf) Cf[(size_t)row * N + col] = v;
                    if (Cb) Cb[(size_t)row * N + col] = f2bf(v);
                    if (Cq) Cq[(size_t)row * N + col] = ftofp8(v);
                }
            }
        }
    }
}

// ---------------- LayerNorm + GELU, one wave per row of 256 ----------------
__global__ __launch_bounds__(256) void ln_gelu_k(const float* __restrict__ y,
                                                 const float* __restrict__ g,
                                                 const float* __restrict__ b,
                                                 float* __restrict__ outf,
                                                 unsigned short* __restrict__ outb) {
    int n = blockIdx.x * 4 + (threadIdx.x >> 6);
    int lane = threadIdx.x & 63;
    float4 v = *reinterpret_cast<const float4*>(&y[(size_t)n * HID + lane * 4]);
    float s = v.x + v.y + v.z + v.w;
    float q = v.x * v.x + v.y * v.y + v.z * v.z + v.w * v.w;
    #pragma unroll
    for (int o = 32; o; o >>= 1) { s += __shfl_xor(s, o); q += __shfl_xor(q, o); }
    float mean = s * (1.0f / HID);
    float var = q * (1.0f / HID) - mean * mean;
    float rs = rsqrtf(var + 1e-5f);
    float4 gv = *reinterpret_cast<const float4*>(&g[lane * 4]);
    float4 bv = *reinterpret_cast<const float4*>(&b[lane * 4]);
    float o0 = gelu_f(gv.x * (v.x - mean) * rs + bv.x);
    float o1 = gelu_f(gv.y * (v.y - mean) * rs + bv.y);
    float o2 = gelu_f(gv.z * (v.z - mean) * rs + bv.z);
    float o3 = gelu_f(gv.w * (v.w - mean) * rs + bv.w);
    if (outf) {
        float4 ov = {o0, o1, o2, o3};
        *reinterpret_cast<float4*>(&outf[(size_t)n * HID + lane * 4]) = ov;
    }
    ushort4 ob;
    ob.x = f2bf(o0); ob.y = f2bf(o1); ob.z = f2bf(o2); ob.w = f2bf(o3);
    *reinterpret_cast<ushort4*>(&outb[(size_t)n * HID + lane * 4]) = ob;
}

// ---------------- CSR build: batched over 3 edge types ----------------
__global__ void hist_k(const int* __restrict__ ei, int* __restrict__ cnt) {
    int gid = blockIdx.x * 256 + threadIdx.x;
    if (gid >= NT * EE) return;
    int t = gid / EE, e = gid - t * EE;
    int dst = ei[(size_t)t * 2 * EE + EE + e];
    atomicAdd(&cnt[t * NN + dst], 1);
}

__global__ __launch_bounds__(256) void scan1_k(const int* __restrict__ cnt, int* __restrict__ bsum, int n) {
    int i = blockIdx.x * 256 + threadIdx.x;
    int v = (i < n) ? cnt[i] : 0;
    #pragma unroll
    for (int o = 32; o; o >>= 1) v += __shfl_xor(v, o);
    __shared__ int s4[4];
    if ((threadIdx.x & 63) == 0) s4[threadIdx.x >> 6] = v;
    __syncthreads();
    if (threadIdx.x == 0) bsum[blockIdx.x] = s4[0] + s4[1] + s4[2] + s4[3];
}

__global__ __launch_bounds__(512) void scan2_k(const int* __restrict__ bsum, int* __restrict__ boff, int nb) {
    __shared__ int sh[512];
    int t = threadIdx.x;
    int v = (t < nb) ? bsum[t] : 0;
    sh[t] = v;
    __syncthreads();
    for (int o = 1; o < 512; o <<= 1) {
        int tv = (t >= o) ? sh[t - o] : 0;
        __syncthreads();
        sh[t] += tv;
        __syncthreads();
    }
    if (t < nb) boff[t] = sh[t] - v;
}

__global__ __launch_bounds__(256) void scan3_k(const int* __restrict__ cnt, const int* __restrict__ boff,
                                               int* __restrict__ roff, int n) {
    int i = blockIdx.x * 256 + threadIdx.x;
    int lane = threadIdx.x & 63, w = threadIdx.x >> 6;
    int v = (i < n) ? cnt[i] : 0;
    int s = v;
    #pragma unroll
    for (int o = 1; o < 64; o <<= 1) {
        int tv = __shfl_up(s, o);
        if (lane >= o) s += tv;
    }
    __shared__ int ws_[4];
    if (lane == 63) ws_[w] = s;
    __syncthreads();
    int add = 0;
    for (int k = 0; k < 4; k++) if (k < w) add += ws_[k];
    int incl = s + add + boff[blockIdx.x];
    if (i < n) roff[i] = incl - v;
    if (i == n - 1) roff[n] = incl;
}

__global__ void scatter_k(const int* __restrict__ ei, const float* __restrict__ ew,
                          const int* __restrict__ roff, int* __restrict__ cur,
                          int* __restrict__ csr_src, float* __restrict__ csr_ew) {
    int gid = blockIdx.x * 256 + threadIdx.x;
    if (gid >= NT * EE) return;
    int t = gid / EE, e = gid - t * EE;
    int src = ei[(size_t)t * 2 * EE + e];
    int dst = ei[(size_t)t * 2 * EE + EE + e];
    int pos = roff[t * NN + dst] + atomicAdd(&cur[t * NN + dst], 1);
    csr_src[pos] = src;
    csr_ew[pos] = ew[gid];
}

// ---------------- edge-weight gate from CSR ----------------
__global__ void ewg_kernel(const int* __restrict__ roff, const float* __restrict__ csr_ew,
                           float* __restrict__ ewg) {
    int n = blockIdx.x * 256 + threadIdx.x;
    if (n >= NN) return;
    float ws = 0.0f;
    int dg = 0;
    for (int t = 0; t < NT; t++) {
        int beg = roff[t * NN + n], end = roff[t * NN + n + 1];
        dg += end - beg;
        for (int e = beg; e < end; e++) ws += csr_ew[e];
    }
    float m = dg > 1 ? (float)dg : 1.0f;
    float z = ws / m;
    ewg[n] = 0.5f + 1.0f / (1.0f + __expf(-z));
}

// ---------------- per-(node,head) attention score inputs (fp8 xpa8 [NN][768]) -----
__global__ __launch_bounds__(256) void compute_s_k(const unsigned char* __restrict__ xpa8,
                                                   const float* __restrict__ asrc,  // [3][256]
                                                   const float* __restrict__ adst,
                                                   float* __restrict__ ss,          // [3][NN][4]
                                                   float* __restrict__ sd) {
    int t = blockIdx.x / (NN / 4);
    int node = (blockIdx.x % (NN / 4)) * 4 + (threadIdx.x >> 6);
    int lane = threadIdx.x & 63;
    uchar4 v = *reinterpret_cast<const uchar4*>(&xpa8[(size_t)node * NP + t * HID + lane * 4]);
    float4 av = *reinterpret_cast<const float4*>(&asrc[t * HID + lane * 4]);
    float4 dv = *reinterpret_cast<const float4*>(&adst[t * HID + lane * 4]);
    float x0 = fp8tof(v.x), x1 = fp8tof(v.y), x2 = fp8tof(v.z), x3 = fp8tof(v.w);
    float p = x0 * av.x + x1 * av.y + x2 * av.z + x3 * av.w;
    float q = x0 * dv.x + x1 * dv.y + x2 * dv.z + x3 * dv.w;
    #pragma unroll
    for (int o = 8; o; o >>= 1) { p += __shfl_xor(p, o); q += __shfl_xor(q, o); }
    if ((lane & 15) == 0) {
        ss[((size_t)t * NN + node) * NH + (lane >> 4)] = p;
        sd[((size_t)t * NN + node) * NH + (lane >> 4)] = q;
    }
}

// ---- fused layer: 3-type GAT agg (no-max softmax, fp8 gathers) + gate + ewg
//      + residual + LN + GELU. Persistent grid-stride waves; hin from bf16 hb.
__global__ __launch_bounds__(256) void layer_k(const unsigned char* __restrict__ xpa8, // [NN][768] fp8
                                               const float* __restrict__ ss,
                                               const float* __restrict__ sd,
                                               const int* __restrict__ roff,
                                               const int* __restrict__ rsrc,
                                               const float* __restrict__ gatb,  // [3][256]
                                               const float* __restrict__ liq,
                                               const float* __restrict__ gW,    // [260]
                                               const float* __restrict__ gb,    // [1]
                                               const float* __restrict__ ewg,
                                               const float* __restrict__ lg,
                                               const float* __restrict__ lb,
                                               float* __restrict__ hout,
                                               unsigned short* __restrict__ hb) { // in+out
    int wid = blockIdx.x * 4 + (threadIdx.x >> 6);
    int lane = threadIdx.x & 63;
    int h = lane >> 4;
    const int nw = LGRID * 4;
    float4 bb0 = *reinterpret_cast<const float4*>(&gatb[lane * 4]);
    float4 bb1 = *reinterpret_cast<const float4*>(&gatb[HID + lane * 4]);
    float4 bb2 = *reinterpret_cast<const float4*>(&gatb[2 * HID + lane * 4]);
    float bs0 = bb0.x + bb1.x + bb2.x;
    float bs1 = bb0.y + bb1.y + bb2.y;
    float bs2 = bb0.z + bb1.z + bb2.z;
    float bs3 = bb0.w + bb1.w + bb2.w;
    float4 gwv = *reinterpret_cast<const float4*>(&gW[lane * 4]);
    float gwl = (lane < 4) ? gW[HID + lane] : 0.0f;
    float gb0 = gb[0];
    float4 lgv = *reinterpret_cast<const float4*>(&lg[lane * 4]);
    float4 lbv = *reinterpret_cast<const float4*>(&lb[lane * 4]);

    for (int node = wid; node < NN; node += nw) {
        float agg0 = 0, agg1 = 0, agg2 = 0, agg3 = 0;
        #pragma unroll
        for (int t = 0; t < NT; t++) {
            int base = t * NN;
            int beg = roff[base + node], end = roff[base + node + 1];
            if (beg == end) continue;
            float sdh = sd[(size_t)(base + node) * NH + h];
            float den = 0, a0 = 0, a1 = 0, a2 = 0, a3 = 0;
            int sp = rsrc[beg];
            float svp = ss[(size_t)(base + sp) * NH + h];
            uchar4 xrp = *reinterpret_cast<const uchar4*>(&xpa8[(size_t)sp * NP + t * HID + lane * 4]);
            for (int e = beg; e < end; e++) {
                float sv_c = svp;
                uchar4 xr_c = xrp;
                int en = (e + 1 < end) ? (e + 1) : e;   // branchless clamp
                int sn = rsrc[en];
                svp = ss[(size_t)(base + sn) * NH + h];
                xrp = *reinterpret_cast<const uchar4*>(&xpa8[(size_t)sn * NP + t * HID + lane * 4]);
                float wg = __expf(lrelu_f(sv_c + sdh));  // no max-shift: |score| < ~1
                den += wg;
                a0 += wg * fp8tof(xr_c.x);
                a1 += wg * fp8tof(xr_c.y);
                a2 += wg * fp8tof(xr_c.z);
                a3 += wg * fp8tof(xr_c.w);
            }
            float inv = 1.0f / (den + 1e-16f);
            agg0 += a0 * inv; agg1 += a1 * inv; agg2 += a2 * inv; agg3 += a3 * inv;
        }
        agg0 += bs0; agg1 += bs1; agg2 += bs2; agg3 += bs3;
        float part = agg0 * gwv.x + agg1 * gwv.y + agg2 * gwv.z + agg3 * gwv.w;
        if (lane < 4) part += liq[node * 4 + lane] * gwl;
        #pragma unroll
        for (int o = 32; o; o >>= 1) part += __shfl_xor(part, o);
        float gate = 1.0f / (1.0f + __expf(-(part + gb0)));
        float eg = ewg[node];
        ushort4 hu = *reinterpret_cast<const ushort4*>(&hb[(size_t)node * HID + lane * 4]);
        float h0 = bf2f(hu.x), h1 = bf2f(hu.y), h2 = bf2f(hu.z), h3 = bf2f(hu.w);
        float v0 = (gate * agg0 + (1.0f - gate) * h0) * eg + h0;
        float v1 = (gate * agg1 + (1.0f - gate) * h1) * eg + h1;
        float v2 = (gate * agg2 + (1.0f - gate) * h2) * eg + h2;
        float v3 = (gate * agg3 + (1.0f - gate) * h3) * eg + h3;
        float s = v0 + v1 + v2 + v3;
        float q = v0 * v0 + v1 * v1 + v2 * v2 + v3 * v3;
        #pragma unroll
        for (int o = 32; o; o >>= 1) { s += __shfl_xor(s, o); q += __shfl_xor(q, o); }
        float mean = s * (1.0f / HID);
        float var = q * (1.0f / HID) - mean * mean;
        float rs = rsqrtf(var + 1e-5f);
        float o0 = gelu_f(lgv.x * (v0 - mean) * rs + lbv.x);
        float o1 = gelu_f(lgv.y * (v1 - mean) * rs + lbv.y);
        float o2 = gelu_f(lgv.z * (v2 - mean) * rs + lbv.z);
        float o3 = gelu_f(lgv.w * (v3 - mean) * rs + lbv.w);
        float4 ov = {o0, o1, o2, o3};
        *reinterpret_cast<float4*>(&hout[(size_t)node * HID + lane * 4]) = ov;
        ushort4 ob;
        ob.x = f2bf(o0); ob.y = f2bf(o1); ob.z = f2bf(o2); ob.w = f2bf(o3);
        *reinterpret_cast<ushort4*>(&hb[(size_t)node * HID + lane * 4]) = ob;
    }
}

// ---------------- column partial sums of ho (N x D) ----------------
__global__ __launch_bounds__(128) void colpart_k(const float* __restrict__ ho,
                                                 float* __restrict__ part) {
    int c = threadIdx.x, b = blockIdx.x;
    float s = 0.0f;
    for (int r = b; r < NN; r += 256) s += ho[(size_t)r * DD + c];
    part[b * DD + c] = s;
}

// ---------------- readout MLP (single block) ----------------
__global__ __launch_bounds__(256) void readout_k(const float* __restrict__ part,
                                                 const float* __restrict__ W1,
                                                 const float* __restrict__ b1,
                                                 const float* __restrict__ W2,
                                                 const float* __restrict__ b2,
                                                 float* __restrict__ surf) {
    __shared__ float m[DD];
    __shared__ float a1[HID];
    int t = threadIdx.x;
    if (t < DD) {
        float s = 0.0f;
        for (int b = 0; b < 256; b++) s += part[b * DD + t];
        m[t] = s / (float)NN;
    }
    __syncthreads();
    float s1 = b1[t];
    for (int k = 0; k < DD; k++) s1 += m[k] * W1[k * HID + t];
    a1[t] = gelu_f(s1);
    __syncthreads();
    float s2 = b2[t];
    for (int k = 0; k < HID; k++) s2 += a1[k] * W2[k * HID + t];
    surf[t] = s2;
}

extern "C" void kernel_launch(void* const* d_in, const int* in_sizes, int n_in,
                              void* d_out, int out_size, void* d_ws, size_t ws_size,
                              hipStream_t stream) {
    const float* x       = (const float*)d_in[0];
    const float* liq     = (const float*)d_in[1];
    const int*   ei      = (const int*)d_in[2];
    const float* ew      = (const float*)d_in[3];
    const float* in_W    = (const float*)d_in[4];
    const float* in_b    = (const float*)d_in[5];
    const float* in_g    = (const float*)d_in[6];
    const float* in_bb   = (const float*)d_in[7];
    const float* gat_W   = (const float*)d_in[8];
    const float* gat_as  = (const float*)d_in[9];
    const float* gat_ad  = (const float*)d_in[10];
    const float* gat_b   = (const float*)d_in[11];
    const float* ln_g    = (const float*)d_in[12];
    const float* ln_b    = (const float*)d_in[13];
    const float* gate_W  = (const float*)d_in[14];
    const float* gate_b  = (const float*)d_in[15];
    const float* out_W1  = (const float*)d_in[16];
    const float* out_b1  = (const float*)d_in[17];
    const float* out_g   = (const float*)d_in[18];
    const float* out_bb  = (const float*)d_in[19];
    const float* out_W2  = (const float*)d_in[20];
    const float* out_b2  = (const float*)d_in[21];
    const float* ro_W1   = (const float*)d_in[22];
    const float* ro_b1   = (const float*)d_in[23];
    const float* ro_W2   = (const float*)d_in[24];
    const float* ro_b2   = (const float*)d_in[25];

    float* out = (float*)d_out;
    float* out_ho   = out;
    float* out_surf = out + (size_t)NN * DD;
    float* out_h[3];
    out_h[0] = out_surf + HID;
    out_h[1] = out_h[0] + (size_t)NN * HID;
    out_h[2] = out_h[1] + (size_t)NN * HID;

    char* wsb = (char*)d_ws;
    size_t off = 0;
    auto alloc = [&](size_t bytes) { char* p = wsb + off; off += (bytes + 255) & ~(size_t)255; return p; };
    // big region: Cf32 (fp32 GEMM out, 41 MB; live only input-proj & head phases)
    //   xpa8 (fp8 [NN][768], 30.7 MB; live only during layers) ALIASES Cf32.
    //   xb (bf16 x, 10.25 MB; live only before input GEMM) sits after Cf32.
    char* big = alloc((size_t)NN * HID * 4 + (size_t)NN * DD * 2);
    float* Cf32 = (float*)big;
    unsigned char* xpa8 = (unsigned char*)big;
    unsigned short* xb = (unsigned short*)(big + (size_t)NN * HID * 4);
    unsigned short* hb = (unsigned short*)alloc((size_t)NN * HID * 2);  // bf16 h shadow
    unsigned short* Wt_in  = (unsigned short*)alloc((size_t)DD * HID * 2);
    unsigned short* Wt_gat = (unsigned short*)alloc((size_t)LL * NT * HID * HID * 2); // [L][768][256]
    unsigned short* Wt_o1  = (unsigned short*)alloc((size_t)HID * HID * 2);
    unsigned short* Wt_o2  = (unsigned short*)alloc((size_t)HID * DD * 2);
    size_t cew_b = (size_t)NT * EE * 4;
    size_t cnt_b = (size_t)NT * NN * 4;
    char* R = alloc(cew_b + cnt_b + 2 * 2048 * 4);
    float* cew = (float*)R;
    int* cnt   = (int*)(R + cew_b);
    int* bsum  = (int*)(R + cew_b + cnt_b);
    int* boff  = bsum + 2048;
    float* ss  = (float*)R;                  // alias: live only after ewg_kernel
    float* sd  = ss + (size_t)NT * NN * NH;
    int* roff  = (int*)alloc(((size_t)NT * NN + 1) * 4);
    int* rsrc  = (int*)alloc((size_t)NT * EE * 4);
    float* ewg = (float*)alloc((size_t)NN * 4);
    float* cpart = (float*)alloc((size_t)256 * DD * 4);

    const int NSC = (NT * NN + 255) / 256;

    // ---- weight conversions ----
    wconv_k<<<(DD * HID + 255) / 256, 256, 0, stream>>>(in_W, Wt_in, 1, DD, HID);
    wconv_k<<<(LL * NT * HID * HID + 255) / 256, 256, 0, stream>>>(gat_W, Wt_gat, LL * NT, HID, HID);
    wconv_k<<<(HID * HID + 255) / 256, 256, 0, stream>>>(out_W1, Wt_o1, 1, HID, HID);
    wconv_k<<<(HID * DD + 255) / 256, 256, 0, stream>>>(out_W2, Wt_o2, 1, HID, DD);
    xconv_k<<<(NN * DD / 4 + 255) / 256, 256, 0, stream>>>(x, xb);

    // ---- input projection + LN + GELU -> h0 (bf16 in hb) ----
    gemm_mfma_k<<<dim3(HID / 128, (NN + 127) / 128), 256, 0, stream>>>(
        xb, Wt_in, in_b, Cf32, nullptr, nullptr, NN, DD, HID);
    ln_gelu_k<<<NN / 4, 256, 0, stream>>>(Cf32, in_g, in_bb, nullptr, hb);

    // ---- CSR build ----
    hipMemsetAsync(cnt, 0, cnt_b, stream);
    hist_k<<<(NT * EE + 255) / 256, 256, 0, stream>>>(ei, cnt);
    scan1_k<<<NSC, 256, 0, stream>>>(cnt, bsum, NT * NN);
    scan2_k<<<1, 512, 0, stream>>>(bsum, boff, NSC);
    scan3_k<<<NSC, 256, 0, stream>>>(cnt, boff, roff, NT * NN);
    hipMemsetAsync(cnt, 0, cnt_b, stream);
    scatter_k<<<(NT * EE + 255) / 256, 256, 0, stream>>>(ei, ew, roff, cnt, rsrc, cew);
    ewg_kernel<<<(NN + 255) / 256, 256, 0, stream>>>(roff, cew, ewg);

    // ---- message-passing layers (projections stored fp8-only) ----
    for (int i = 0; i < LL; i++) {
        gemm_mfma_k<<<dim3(NP / 128, (NN + 127) / 128), 256, 0, stream>>>(
            hb, Wt_gat + (size_t)i * NP * HID, nullptr, nullptr, nullptr, xpa8, NN, HID, NP);
        compute_s_k<<<NT * (NN / 4), 256, 0, stream>>>(
            xpa8, gat_as + (size_t)i * NT * HID, gat_ad + (size_t)i * NT * HID, ss, sd);
        layer_k<<<LGRID, 256, 0, stream>>>(
            xpa8, ss, sd, roff, rsrc, gat_b + (size_t)i * NT * HID,
            liq, gate_W, gate_b, ewg, ln_g + i * HID, ln_b + i * HID,
            out_h[i], hb);
    }

    // ---- output head ----
    gemm_mfma_k<<<dim3(HID / 128, (NN + 127) / 128), 256, 0, stream>>>(
        hb, Wt_o1, out_b1, Cf32, nullptr, nullptr, NN, HID, HID);
    ln_gelu_k<<<NN / 4, 256, 0, stream>>>(Cf32, out_g, out_bb, nullptr, hb);
    gemm_mfma_k<<<dim3(DD / 128, (NN + 127) / 128), 256, 0, stream>>>(
        hb, Wt_o2, out_b2, out_ho, nullptr, nullptr, NN, HID, DD);

    // ---- readout ----
    colpart_k<<<256, 128, 0, stream>>>(out_ho, cpart);
    readout_k<<<1, 256, 0, stream>>>(cpart, ro_W1, ro_b1, ro_W2, ro_b2, out_surf);
}

// Round 7
// 814.335 us; speedup vs baseline: 3.4472x; 1.0133x over previous
//
#include <hip/hip_runtime.h>
#include <hip/hip_bf16.h>
#include <math.h>

#define NN 40000
#define EE 320000
#define NT 3
#define LL 3
#define DD 128
#define HID 256
#define NH 4
#define CC 64
#define NP 768   // NT*HID: batched projection width
#define LGRID 2048  // layer_k persistent blocks (8192 waves)

typedef __attribute__((ext_vector_type(8))) short short8;
typedef __attribute__((ext_vector_type(4))) float f32x4;

__device__ __forceinline__ float gelu_f(float x) {
    return 0.5f * x * (1.0f + erff(x * 0.70710678118654752440f));
}
__device__ __forceinline__ float lrelu_f(float x) {
    return x > 0.0f ? x : 0.2f * x;
}
__device__ __forceinline__ float bf2f(unsigned short u) {
    unsigned int x = ((unsigned int)u) << 16;
    float f;
    __builtin_memcpy(&f, &x, 4);
    return f;
}
__device__ __forceinline__ unsigned short f2bf(float f) {
    __hip_bfloat16 h = __float2bfloat16(f);
    unsigned short u;
    __builtin_memcpy(&u, &h, 2);
    return u;
}
__device__ __forceinline__ void gload16(const void* g, void* l) {
    __builtin_amdgcn_global_load_lds(
        (const __attribute__((address_space(1))) unsigned int*)g,
        (__attribute__((address_space(3))) unsigned int*)l, 16, 0, 0);
}

// ---------------- weight transpose + bf16 convert: W[m][K][N] -> Wt[m][N][K] ----------------
__global__ void wconv_k(const float* __restrict__ W, unsigned short* __restrict__ Wt,
                        int nmat, int K, int N) {
    int idx = blockIdx.x * 256 + threadIdx.x;
    int tot = nmat * K * N;
    if (idx >= tot) return;
    int m = idx / (K * N);
    int rem = idx - m * (K * N);
    int k = rem / N;
    int n = rem - k * N;
    Wt[(size_t)m * K * N + (size_t)n * K + k] = f2bf(W[idx]);
}

// ---------------- x fp32 -> bf16 ----------------
__global__ void xconv_k(const float* __restrict__ x, unsigned short* __restrict__ xb) {
    int idx = blockIdx.x * 256 + threadIdx.x;
    if (idx >= NN * DD / 4) return;
    float4 v = *reinterpret_cast<const float4*>(&x[(size_t)idx * 4]);
    ushort4 o;
    o.x = f2bf(v.x); o.y = f2bf(v.y); o.z = f2bf(v.z); o.w = f2bf(v.w);
    *reinterpret_cast<ushort4*>(&xb[(size_t)idx * 4]) = o;
}

// ---------------- MFMA bf16 GEMM: C[M][N] = A[M][K] @ Bt[N][K]^T (+bias) ----------------
// XCD-chunked bijective block swizzle (N-tile fastest within an XCD chunk).
__global__ __launch_bounds__(256) void gemm_mfma_k(const unsigned short* __restrict__ A,
                                                   const unsigned short* __restrict__ Bt,
                                                   const float* __restrict__ bias,
                                                   float* __restrict__ Cf,
                                                   unsigned short* __restrict__ Cb,
                                                   int M, int K, int N) {
    __shared__ __align__(16) short As[128 * 32];
    __shared__ __align__(16) short Bs[128 * 32];
    int gdx = gridDim.x;
    int nwg = gdx * gridDim.y;
    int f = blockIdx.y * gdx + blockIdx.x;
    int q8 = nwg >> 3, r8 = nwg & 7;
    int xcd = f & 7, idx8 = f >> 3;
    int nf = (xcd < r8 ? xcd * (q8 + 1) : r8 * (q8 + 1) + (xcd - r8) * q8) + idx8;
    int bn = (nf % gdx) * 128;
    int bm = (nf / gdx) * 128;
    int tid = threadIdx.x;
    int lane = tid & 63, w = tid >> 6;
    int wr = w >> 1, wc = w & 1;
    int l16 = lane & 15, kgrp = lane >> 4;
    f32x4 acc[4][4] = {};
    for (int k0 = 0; k0 < K; k0 += 32) {
        #pragma unroll
        for (int i = 0; i < 2; i++) {
            int chunk = (i * 4 + w) * 64 + lane;     // 0..511
            int row = chunk >> 2, kq = chunk & 3;
            int grow = bm + row; if (grow > M - 1) grow = M - 1;
            gload16(A + (size_t)grow * K + k0 + kq * 8, &As[(i * 4 + w) * 512]);
        }
        #pragma unroll
        for (int i = 0; i < 2; i++) {
            int chunk = (i * 4 + w) * 64 + lane;
            int row = chunk >> 2, kq = chunk & 3;
            gload16(Bt + (size_t)(bn + row) * K + k0 + kq * 8, &Bs[(i * 4 + w) * 512]);
        }
        __syncthreads();
        short8 af[4], bf[4];
        #pragma unroll
        for (int mi = 0; mi < 4; mi++) {
            int row = wr * 64 + mi * 16 + l16;
            af[mi] = *reinterpret_cast<const short8*>(&As[row * 32 + kgrp * 8]);
        }
        #pragma unroll
        for (int ni = 0; ni < 4; ni++) {
            int nrow = wc * 64 + ni * 16 + l16;
            bf[ni] = *reinterpret_cast<const short8*>(&Bs[nrow * 32 + kgrp * 8]);
        }
        #pragma unroll
        for (int mi = 0; mi < 4; mi++)
            #pragma unroll
            for (int ni = 0; ni < 4; ni++)
                acc[mi][ni] = __builtin_amdgcn_mfma_f32_16x16x32_bf16(af[mi], bf[ni], acc[mi][ni], 0, 0, 0);
        __syncthreads();
    }
    #pragma unroll
    for (int mi = 0; mi < 4; mi++) {
        #pragma unroll
        for (int r = 0; r < 4; r++) {
            int row = bm + wr * 64 + mi * 16 + (lane >> 4) * 4 + r;
            if (row < M) {
                #pragma unroll
                for (int ni = 0; ni < 4; ni++) {
                    int col = bn + wc * 64 + ni * 16 + l16;
                    float v = acc[mi][ni][r] + (bias ? bias[col] : 0.0f);
                    if (Cf) Cf[(size_t)row * N + col] = v;
                    if (Cb) Cb[(size_t)row * N + col] = f2bf(v);
                }
            }
        }
    }
}

// ---------------- LayerNorm + GELU, one wave per row of 256 ----------------
__global__ __launch_bounds__(256) void ln_gelu_k(const float* __restrict__ y,
                                                 const float* __restrict__ g,
                                                 const float* __restrict__ b,
                                                 float* __restrict__ outf,
                                                 unsigned short* __restrict__ outb) {
    int n = blockIdx.x * 4 + (threadIdx.x >> 6);
    int lane = threadIdx.x & 63;
    float4 v = *reinterpret_cast<const float4*>(&y[(size_t)n * HID + lane * 4]);
    float s = v.x + v.y + v.z + v.w;
    float q = v.x * v.x + v.y * v.y + v.z * v.z + v.w * v.w;
    #pragma unroll
    for (int o = 32; o; o >>= 1) { s += __shfl_xor(s, o); q += __shfl_xor(q, o); }
    float mean = s * (1.0f / HID);
    float var = q * (1.0f / HID) - mean * mean;
    float rs = rsqrtf(var + 1e-5f);
    float4 gv = *reinterpret_cast<const float4*>(&g[lane * 4]);
    float4 bv = *reinterpret_cast<const float4*>(&b[lane * 4]);
    float o0 = gelu_f(gv.x * (v.x - mean) * rs + bv.x);
    float o1 = gelu_f(gv.y * (v.y - mean) * rs + bv.y);
    float o2 = gelu_f(gv.z * (v.z - mean) * rs + bv.z);
    float o3 = gelu_f(gv.w * (v.w - mean) * rs + bv.w);
    if (outf) {
        float4 ov = {o0, o1, o2, o3};
        *reinterpret_cast<float4*>(&outf[(size_t)n * HID + lane * 4]) = ov;
    }
    ushort4 ob;
    ob.x = f2bf(o0); ob.y = f2bf(o1); ob.z = f2bf(o2); ob.w = f2bf(o3);
    *reinterpret_cast<ushort4*>(&outb[(size_t)n * HID + lane * 4]) = ob;
}

// ---------------- CSR build: batched over 3 edge types ----------------
__global__ void hist_k(const int* __restrict__ ei, int* __restrict__ cnt) {
    int gid = blockIdx.x * 256 + threadIdx.x;
    if (gid >= NT * EE) return;
    int t = gid / EE, e = gid - t * EE;
    int dst = ei[(size_t)t * 2 * EE + EE + e];
    atomicAdd(&cnt[t * NN + dst], 1);
}

__global__ __launch_bounds__(256) void scan1_k(const int* __restrict__ cnt, int* __restrict__ bsum, int n) {
    int i = blockIdx.x * 256 + threadIdx.x;
    int v = (i < n) ? cnt[i] : 0;
    #pragma unroll
    for (int o = 32; o; o >>= 1) v += __shfl_xor(v, o);
    __shared__ int s4[4];
    if ((threadIdx.x & 63) == 0) s4[threadIdx.x >> 6] = v;
    __syncthreads();
    if (threadIdx.x == 0) bsum[blockIdx.x] = s4[0] + s4[1] + s4[2] + s4[3];
}

__global__ __launch_bounds__(512) void scan2_k(const int* __restrict__ bsum, int* __restrict__ boff, int nb) {
    __shared__ int sh[512];
    int t = threadIdx.x;
    int v = (t < nb) ? bsum[t] : 0;
    sh[t] = v;
    __syncthreads();
    for (int o = 1; o < 512; o <<= 1) {
        int tv = (t >= o) ? sh[t - o] : 0;
        __syncthreads();
        sh[t] += tv;
        __syncthreads();
    }
    if (t < nb) boff[t] = sh[t] - v;
}

__global__ __launch_bounds__(256) void scan3_k(const int* __restrict__ cnt, const int* __restrict__ boff,
                                               int* __restrict__ roff, int n) {
    int i = blockIdx.x * 256 + threadIdx.x;
    int lane = threadIdx.x & 63, w = threadIdx.x >> 6;
    int v = (i < n) ? cnt[i] : 0;
    int s = v;
    #pragma unroll
    for (int o = 1; o < 64; o <<= 1) {
        int tv = __shfl_up(s, o);
        if (lane >= o) s += tv;
    }
    __shared__ int ws_[4];
    if (lane == 63) ws_[w] = s;
    __syncthreads();
    int add = 0;
    for (int k = 0; k < 4; k++) if (k < w) add += ws_[k];
    int incl = s + add + boff[blockIdx.x];
    if (i < n) roff[i] = incl - v;
    if (i == n - 1) roff[n] = incl;
}

__global__ void scatter_k(const int* __restrict__ ei, const float* __restrict__ ew,
                          const int* __restrict__ roff, int* __restrict__ cur,
                          int* __restrict__ csr_src, float* __restrict__ csr_ew) {
    int gid = blockIdx.x * 256 + threadIdx.x;
    if (gid >= NT * EE) return;
    int t = gid / EE, e = gid - t * EE;
    int src = ei[(size_t)t * 2 * EE + e];
    int dst = ei[(size_t)t * 2 * EE + EE + e];
    int pos = roff[t * NN + dst] + atomicAdd(&cur[t * NN + dst], 1);
    csr_src[pos] = src;
    csr_ew[pos] = ew[gid];
}

// ---------------- edge-weight gate from CSR ----------------
__global__ void ewg_kernel(const int* __restrict__ roff, const float* __restrict__ csr_ew,
                           float* __restrict__ ewg) {
    int n = blockIdx.x * 256 + threadIdx.x;
    if (n >= NN) return;
    float ws = 0.0f;
    int dg = 0;
    for (int t = 0; t < NT; t++) {
        int beg = roff[t * NN + n], end = roff[t * NN + n + 1];
        dg += end - beg;
        for (int e = beg; e < end; e++) ws += csr_ew[e];
    }
    float m = dg > 1 ? (float)dg : 1.0f;
    float z = ws / m;
    ewg[n] = 0.5f + 1.0f / (1.0f + __expf(-z));
}

// ---------------- per-(node,head) attention score inputs (bf16 xpa [NN][768]) -----
__global__ __launch_bounds__(256) void compute_s_k(const unsigned short* __restrict__ xpa,
                                                   const float* __restrict__ asrc,  // [3][256]
                                                   const float* __restrict__ adst,
                                                   float* __restrict__ ss,          // [3][NN][4]
                                                   float* __restrict__ sd) {
    int t = blockIdx.x / (NN / 4);
    int node = (blockIdx.x % (NN / 4)) * 4 + (threadIdx.x >> 6);
    int lane = threadIdx.x & 63;
    ushort4 v = *reinterpret_cast<const ushort4*>(&xpa[(size_t)node * NP + t * HID + lane * 4]);
    float4 av = *reinterpret_cast<const float4*>(&asrc[t * HID + lane * 4]);
    float4 dv = *reinterpret_cast<const float4*>(&adst[t * HID + lane * 4]);
    float x0 = bf2f(v.x), x1 = bf2f(v.y), x2 = bf2f(v.z), x3 = bf2f(v.w);
    float p = x0 * av.x + x1 * av.y + x2 * av.z + x3 * av.w;
    float q = x0 * dv.x + x1 * dv.y + x2 * dv.z + x3 * dv.w;
    #pragma unroll
    for (int o = 8; o; o >>= 1) { p += __shfl_xor(p, o); q += __shfl_xor(q, o); }
    if ((lane & 15) == 0) {
        ss[((size_t)t * NN + node) * NH + (lane >> 4)] = p;
        sd[((size_t)t * NN + node) * NH + (lane >> 4)] = q;
    }
}

// ---- fused layer: 3-type GAT agg (no-max softmax, chunk-4 MLP gathers) + gate + ewg
//      + residual + LN + GELU. Persistent grid-stride waves; hin from bf16 hb.
__global__ __launch_bounds__(256) void layer_k(const unsigned short* __restrict__ xpa, // [NN][768]
                                               const float* __restrict__ ss,
                                               const float* __restrict__ sd,
                                               const int* __restrict__ roff,
                                               const int* __restrict__ rsrc,
                                               const float* __restrict__ gatb,  // [3][256]
                                               const float* __restrict__ liq,
                                               const float* __restrict__ gW,    // [260]
                                               const float* __restrict__ gb,    // [1]
                                               const float* __restrict__ ewg,
                                               const float* __restrict__ lg,
                                               const float* __restrict__ lb,
                                               float* __restrict__ hout,
                                               unsigned short* __restrict__ hb) { // in+out
    int wid = blockIdx.x * 4 + (threadIdx.x >> 6);
    int lane = threadIdx.x & 63;
    int h = lane >> 4;
    const int nw = LGRID * 4;
    float4 bb0 = *reinterpret_cast<const float4*>(&gatb[lane * 4]);
    float4 bb1 = *reinterpret_cast<const float4*>(&gatb[HID + lane * 4]);
    float4 bb2 = *reinterpret_cast<const float4*>(&gatb[2 * HID + lane * 4]);
    float bs0 = bb0.x + bb1.x + bb2.x;
    float bs1 = bb0.y + bb1.y + bb2.y;
    float bs2 = bb0.z + bb1.z + bb2.z;
    float bs3 = bb0.w + bb1.w + bb2.w;
    float4 gwv = *reinterpret_cast<const float4*>(&gW[lane * 4]);
    float gwl = (lane < 4) ? gW[HID + lane] : 0.0f;
    float gb0 = gb[0];
    float4 lgv = *reinterpret_cast<const float4*>(&lg[lane * 4]);
    float4 lbv = *reinterpret_cast<const float4*>(&lb[lane * 4]);

    for (int node = wid; node < NN; node += nw) {
        float agg0 = 0, agg1 = 0, agg2 = 0, agg3 = 0;
        #pragma unroll
        for (int t = 0; t < NT; t++) {
            int base = t * NN;
            int beg = roff[base + node], end = roff[base + node + 1];
            if (beg == end) continue;
            float sdh = sd[(size_t)(base + node) * NH + h];
            float den = 0, a0 = 0, a1 = 0, a2 = 0, a3 = 0;
            int last = end - 1;
            for (int e = beg; e < end; e += 4) {
                // 4-wide chunk: all 12 loads issued before any use (MLP = 8+)
                int e1 = e + 1 > last ? last : e + 1;
                int e2 = e + 2 > last ? last : e + 2;
                int e3 = e + 3 > last ? last : e + 3;
                int s0 = rsrc[e], s1 = rsrc[e1], s2 = rsrc[e2], s3 = rsrc[e3];
                float sv0 = ss[(size_t)(base + s0) * NH + h];
                float sv1 = ss[(size_t)(base + s1) * NH + h];
                float sv2 = ss[(size_t)(base + s2) * NH + h];
                float sv3 = ss[(size_t)(base + s3) * NH + h];
                ushort4 x0 = *reinterpret_cast<const ushort4*>(&xpa[(size_t)s0 * NP + t * HID + lane * 4]);
                ushort4 x1 = *reinterpret_cast<const ushort4*>(&xpa[(size_t)s1 * NP + t * HID + lane * 4]);
                ushort4 x2 = *reinterpret_cast<const ushort4*>(&xpa[(size_t)s2 * NP + t * HID + lane * 4]);
                ushort4 x3 = *reinterpret_cast<const ushort4*>(&xpa[(size_t)s3 * NP + t * HID + lane * 4]);
                float w0 = __expf(lrelu_f(sv0 + sdh));                             // no max-shift
                float w1 = (e + 1 <= last) ? __expf(lrelu_f(sv1 + sdh)) : 0.0f;    // masked tail
                float w2 = (e + 2 <= last) ? __expf(lrelu_f(sv2 + sdh)) : 0.0f;
                float w3 = (e + 3 <= last) ? __expf(lrelu_f(sv3 + sdh)) : 0.0f;
                den += (w0 + w1) + (w2 + w3);
                a0 += w0 * bf2f(x0.x) + w1 * bf2f(x1.x) + w2 * bf2f(x2.x) + w3 * bf2f(x3.x);
                a1 += w0 * bf2f(x0.y) + w1 * bf2f(x1.y) + w2 * bf2f(x2.y) + w3 * bf2f(x3.y);
                a2 += w0 * bf2f(x0.z) + w1 * bf2f(x1.z) + w2 * bf2f(x2.z) + w3 * bf2f(x3.z);
                a3 += w0 * bf2f(x0.w) + w1 * bf2f(x1.w) + w2 * bf2f(x2.w) + w3 * bf2f(x3.w);
            }
            float inv = 1.0f / (den + 1e-16f);
            agg0 += a0 * inv; agg1 += a1 * inv; agg2 += a2 * inv; agg3 += a3 * inv;
        }
        agg0 += bs0; agg1 += bs1; agg2 += bs2; agg3 += bs3;
        float part = agg0 * gwv.x + agg1 * gwv.y + agg2 * gwv.z + agg3 * gwv.w;
        if (lane < 4) part += liq[node * 4 + lane] * gwl;
        #pragma unroll
        for (int o = 32; o; o >>= 1) part += __shfl_xor(part, o);
        float gate = 1.0f / (1.0f + __expf(-(part + gb0)));
        float eg = ewg[node];
        ushort4 hu = *reinterpret_cast<const ushort4*>(&hb[(size_t)node * HID + lane * 4]);
        float h0 = bf2f(hu.x), h1 = bf2f(hu.y), h2 = bf2f(hu.z), h3 = bf2f(hu.w);
        float v0 = (gate * agg0 + (1.0f - gate) * h0) * eg + h0;
        float v1 = (gate * agg1 + (1.0f - gate) * h1) * eg + h1;
        float v2 = (gate * agg2 + (1.0f - gate) * h2) * eg + h2;
        float v3 = (gate * agg3 + (1.0f - gate) * h3) * eg + h3;
        float s = v0 + v1 + v2 + v3;
        float q = v0 * v0 + v1 * v1 + v2 * v2 + v3 * v3;
        #pragma unroll
        for (int o = 32; o; o >>= 1) { s += __shfl_xor(s, o); q += __shfl_xor(q, o); }
        float mean = s * (1.0f / HID);
        float var = q * (1.0f / HID) - mean * mean;
        float rs = rsqrtf(var + 1e-5f);
        float o0 = gelu_f(lgv.x * (v0 - mean) * rs + lbv.x);
        float o1 = gelu_f(lgv.y * (v1 - mean) * rs + lbv.y);
        float o2 = gelu_f(lgv.z * (v2 - mean) * rs + lbv.z);
        float o3 = gelu_f(lgv.w * (v3 - mean) * rs + lbv.w);
        float4 ov = {o0, o1, o2, o3};
        *reinterpret_cast<float4*>(&hout[(size_t)node * HID + lane * 4]) = ov;
        ushort4 ob;
        ob.x = f2bf(o0); ob.y = f2bf(o1); ob.z = f2bf(o2); ob.w = f2bf(o3);
        *reinterpret_cast<ushort4*>(&hb[(size_t)node * HID + lane * 4]) = ob;
    }
}

// ---------------- column partial sums of ho (N x D) ----------------
__global__ __launch_bounds__(128) void colpart_k(const float* __restrict__ ho,
                                                 float* __restrict__ part) {
    int c = threadIdx.x, b = blockIdx.x;
    float s = 0.0f;
    for (int r = b; r < NN; r += 256) s += ho[(size_t)r * DD + c];
    part[b * DD + c] = s;
}

// ---------------- readout MLP (single block) ----------------
__global__ __launch_bounds__(256) void readout_k(const float* __restrict__ part,
                                                 const float* __restrict__ W1,
                                                 const float* __restrict__ b1,
                                                 const float* __restrict__ W2,
                                                 const float* __restrict__ b2,
                                                 float* __restrict__ surf) {
    __shared__ float m[DD];
    __shared__ float a1[HID];
    int t = threadIdx.x;
    if (t < DD) {
        float s = 0.0f;
        for (int b = 0; b < 256; b++) s += part[b * DD + t];
        m[t] = s / (float)NN;
    }
    __syncthreads();
    float s1 = b1[t];
    for (int k = 0; k < DD; k++) s1 += m[k] * W1[k * HID + t];
    a1[t] = gelu_f(s1);
    __syncthreads();
    float s2 = b2[t];
    for (int k = 0; k < HID; k++) s2 += a1[k] * W2[k * HID + t];
    surf[t] = s2;
}

extern "C" void kernel_launch(void* const* d_in, const int* in_sizes, int n_in,
                              void* d_out, int out_size, void* d_ws, size_t ws_size,
                              hipStream_t stream) {
    const float* x       = (const float*)d_in[0];
    const float* liq     = (const float*)d_in[1];
    const int*   ei      = (const int*)d_in[2];
    const float* ew      = (const float*)d_in[3];
    const float* in_W    = (const float*)d_in[4];
    const float* in_b    = (const float*)d_in[5];
    const float* in_g    = (const float*)d_in[6];
    const float* in_bb   = (const float*)d_in[7];
    const float* gat_W   = (const float*)d_in[8];
    const float* gat_as  = (const float*)d_in[9];
    const float* gat_ad  = (const float*)d_in[10];
    const float* gat_b   = (const float*)d_in[11];
    const float* ln_g    = (const float*)d_in[12];
    const float* ln_b    = (const float*)d_in[13];
    const float* gate_W  = (const float*)d_in[14];
    const float* gate_b  = (const float*)d_in[15];
    const float* out_W1  = (const float*)d_in[16];
    const float* out_b1  = (const float*)d_in[17];
    const float* out_g   = (const float*)d_in[18];
    const float* out_bb  = (const float*)d_in[19];
    const float* out_W2  = (const float*)d_in[20];
    const float* out_b2  = (const float*)d_in[21];
    const float* ro_W1   = (const float*)d_in[22];
    const float* ro_b1   = (const float*)d_in[23];
    const float* ro_W2   = (const float*)d_in[24];
    const float* ro_b2   = (const float*)d_in[25];

    float* out = (float*)d_out;
    float* out_ho   = out;
    float* out_surf = out + (size_t)NN * DD;
    float* out_h[3];
    out_h[0] = out_surf + HID;
    out_h[1] = out_h[0] + (size_t)NN * HID;
    out_h[2] = out_h[1] + (size_t)NN * HID;

    char* wsb = (char*)d_ws;
    size_t off = 0;
    auto alloc = [&](size_t bytes) { char* p = wsb + off; off += (bytes + 255) & ~(size_t)255; return p; };
    // xpa bf16 [NN][768] (61.4 MB). Aliases inside it: Cf32 (fp32 GEMM out, 41 MB)
    // at the front; xb (bf16 x, 10.25 MB) after Cf32. Both dead before layer 0's GEMM.
    unsigned short* xpa = (unsigned short*)alloc((size_t)NN * NP * 2);
    float* Cf32 = (float*)xpa;
    unsigned short* xb = xpa + (size_t)NN * 512;
    unsigned short* hb = (unsigned short*)alloc((size_t)NN * HID * 2);  // bf16 h shadow
    unsigned short* Wt_in  = (unsigned short*)alloc((size_t)DD * HID * 2);
    unsigned short* Wt_gat = (unsigned short*)alloc((size_t)LL * NT * HID * HID * 2); // [L][768][256]
    unsigned short* Wt_o1  = (unsigned short*)alloc((size_t)HID * HID * 2);
    unsigned short* Wt_o2  = (unsigned short*)alloc((size_t)HID * DD * 2);
    size_t cew_b = (size_t)NT * EE * 4;
    size_t cnt_b = (size_t)NT * NN * 4;
    char* R = alloc(cew_b + cnt_b + 2 * 2048 * 4);
    float* cew = (float*)R;
    int* cnt   = (int*)(R + cew_b);
    int* bsum  = (int*)(R + cew_b + cnt_b);
    int* boff  = bsum + 2048;
    float* ss  = (float*)R;                  // alias: live only after ewg_kernel
    float* sd  = ss + (size_t)NT * NN * NH;
    int* roff  = (int*)alloc(((size_t)NT * NN + 1) * 4);
    int* rsrc  = (int*)alloc((size_t)NT * EE * 4);
    float* ewg = (float*)alloc((size_t)NN * 4);
    float* cpart = (float*)alloc((size_t)256 * DD * 4);

    const int NSC = (NT * NN + 255) / 256;

    // ---- weight conversions ----
    wconv_k<<<(DD * HID + 255) / 256, 256, 0, stream>>>(in_W, Wt_in, 1, DD, HID);
    wconv_k<<<(LL * NT * HID * HID + 255) / 256, 256, 0, stream>>>(gat_W, Wt_gat, LL * NT, HID, HID);
    wconv_k<<<(HID * HID + 255) / 256, 256, 0, stream>>>(out_W1, Wt_o1, 1, HID, HID);
    wconv_k<<<(HID * DD + 255) / 256, 256, 0, stream>>>(out_W2, Wt_o2, 1, HID, DD);
    xconv_k<<<(NN * DD / 4 + 255) / 256, 256, 0, stream>>>(x, xb);

    // ---- input projection + LN + GELU -> h0 (bf16 in hb) ----
    gemm_mfma_k<<<dim3(HID / 128, (NN + 127) / 128), 256, 0, stream>>>(
        xb, Wt_in, in_b, Cf32, nullptr, NN, DD, HID);
    ln_gelu_k<<<NN / 4, 256, 0, stream>>>(Cf32, in_g, in_bb, nullptr, hb);

    // ---- CSR build ----
    hipMemsetAsync(cnt, 0, cnt_b, stream);
    hist_k<<<(NT * EE + 255) / 256, 256, 0, stream>>>(ei, cnt);
    scan1_k<<<NSC, 256, 0, stream>>>(cnt, bsum, NT * NN);
    scan2_k<<<1, 512, 0, stream>>>(bsum, boff, NSC);
    scan3_k<<<NSC, 256, 0, stream>>>(cnt, boff, roff, NT * NN);
    hipMemsetAsync(cnt, 0, cnt_b, stream);
    scatter_k<<<(NT * EE + 255) / 256, 256, 0, stream>>>(ei, ew, roff, cnt, rsrc, cew);
    ewg_kernel<<<(NN + 255) / 256, 256, 0, stream>>>(roff, cew, ewg);

    // ---- message-passing layers ----
    for (int i = 0; i < LL; i++) {
        gemm_mfma_k<<<dim3(NP / 128, (NN + 127) / 128), 256, 0, stream>>>(
            hb, Wt_gat + (size_t)i * NP * HID, nullptr, nullptr, xpa, NN, HID, NP);
        compute_s_k<<<NT * (NN / 4), 256, 0, stream>>>(
            xpa, gat_as + (size_t)i * NT * HID, gat_ad + (size_t)i * NT * HID, ss, sd);
        layer_k<<<LGRID, 256, 0, stream>>>(
            xpa, ss, sd, roff, rsrc, gat_b + (size_t)i * NT * HID,
            liq, gate_W, gate_b, ewg, ln_g + i * HID, ln_b + i * HID,
            out_h[i], hb);
    }

    // ---- output head ----
    gemm_mfma_k<<<dim3(HID / 128, (NN + 127) / 128), 256, 0, stream>>>(
        hb, Wt_o1, out_b1, Cf32, nullptr, NN, HID, HID);
    ln_gelu_k<<<NN / 4, 256, 0, stream>>>(Cf32, out_g, out_bb, nullptr, hb);
    gemm_mfma_k<<<dim3(DD / 128, (NN + 127) / 128), 256, 0, stream>>>(
        hb, Wt_o2, out_b2, out_ho, nullptr, NN, HID, DD);

    // ---- readout ----
    colpart_k<<<256, 128, 0, stream>>>(out_ho, cpart);
    readout_k<<<1, 256, 0, stream>>>(cpart, ro_W1, ro_b1, ro_W2, ro_b2, out_surf);
}